// Round 8
// baseline (1566.144 us; speedup 1.0000x reference)
//
#include <hip/hip_runtime.h>
#include <hip/hip_bf16.h>
#include <stdint.h>

#define HH 256
#define BN_EPS 1e-5f
#define CHUNK 256
#define NSLOT 12   // stats slots: layer i -> 2i (inner), 2i+1 (outer); classifier -> 10

static inline int cdiv(int a, int b) { return (a + b - 1) / b; }

typedef _Float16 f16x8 __attribute__((ext_vector_type(8)));
typedef __attribute__((ext_vector_type(4))) float f32x4;

__device__ __forceinline__ unsigned short f2h(float f) {
    _Float16 h = (_Float16)f;            // v_cvt_f16_f32, RNE
    unsigned short u;
    __builtin_memcpy(&u, &h, 2);
    return u;
}
__device__ __forceinline__ float h2f(unsigned short u) {
    _Float16 h;
    __builtin_memcpy(&h, &u, 2);
    return (float)h;
}

__device__ __forceinline__ void gload16(const void* g, void* lds) {
    __builtin_amdgcn_global_load_lds((const __attribute__((address_space(1))) unsigned int*)g,
                                     (__attribute__((address_space(3))) unsigned int*)lds, 16, 0, 0);
}

// derive BN scale/shift for one channel from raw sums
__device__ __forceinline__ void bn_derive(const float* __restrict__ stats, const float* __restrict__ g,
                                          const float* __restrict__ b, float invM, int c,
                                          float& sc, float& sh) {
    float mu = stats[c] * invM;
    float var = stats[HH + c] * invM - mu * mu;
    float rstd = rsqrtf(var + BN_EPS);
    sc = rstd * g[c];
    sh = b[c] - mu * sc;
}

// ---------------- embed -> f16 ----------------
__global__ void embed_kernel(const float* __restrict__ xa, const float* __restrict__ xp,
                             const float* __restrict__ aw, const float* __restrict__ ab,
                             const float* __restrict__ pw, const float* __restrict__ pb,
                             unsigned short* __restrict__ h, int N) {
    int n = blockIdx.x;
    int c = threadIdx.x;
    if (n >= N) return;
    float acc = ab[c] + pb[c];
#pragma unroll
    for (int k = 0; k < 9; ++k) acc += xa[n * 9 + k] * aw[k * HH + c];
#pragma unroll
    for (int k = 0; k < 8; ++k) acc += xp[n * 8 + k] * pw[k * HH + c];
    h[(size_t)n * HH + c] = f2h(acc);
}

// ---------------- CSR build ----------------
__global__ void zero_int_kernel(int* __restrict__ p, int n) {
    int i = blockIdx.x * blockDim.x + threadIdx.x;
    if (i < n) p[i] = 0;
}

__global__ void hist_kernel(const int* __restrict__ ei, int* __restrict__ deg, int E) {
    int e = blockIdx.x * blockDim.x + threadIdx.x;
    if (e < E) atomicAdd(&deg[ei[(size_t)E + e]], 1);
}

__global__ void ps1_kernel(const int* __restrict__ deg, int* __restrict__ chunkSum, int N) {
    __shared__ int sm[CHUNK];
    int i = blockIdx.x * CHUNK + threadIdx.x;
    sm[threadIdx.x] = (i < N) ? deg[i] : 0;
    __syncthreads();
    for (int off = CHUNK / 2; off > 0; off >>= 1) {
        if (threadIdx.x < off) sm[threadIdx.x] += sm[threadIdx.x + off];
        __syncthreads();
    }
    if (threadIdx.x == 0) chunkSum[blockIdx.x] = sm[0];
}

__global__ void ps2_kernel(const int* __restrict__ chunkSum, int* __restrict__ chunkOff,
                           int nc, int* __restrict__ offs, int N, int E) {
    __shared__ int sm[CHUNK];
    int t = threadIdx.x;
    int own = (t < nc) ? chunkSum[t] : 0;
    sm[t] = own;
    for (int off = 1; off < CHUNK; off <<= 1) {
        __syncthreads();
        int v = (t >= off) ? sm[t - off] : 0;
        __syncthreads();
        sm[t] += v;
    }
    if (t < nc) chunkOff[t] = sm[t] - own;
    if (t == 0) offs[N] = E;
}

__global__ void ps3_kernel(const int* __restrict__ deg, const int* __restrict__ chunkOff,
                           int* __restrict__ offs, int* __restrict__ cursor, int N) {
    __shared__ int sm[CHUNK];
    int t = threadIdx.x;
    int i = blockIdx.x * CHUNK + t;
    int own = (i < N) ? deg[i] : 0;
    sm[t] = own;
    for (int off = 1; off < CHUNK; off <<= 1) {
        __syncthreads();
        int v = (t >= off) ? sm[t - off] : 0;
        __syncthreads();
        sm[t] += v;
    }
    if (i < N) {
        int o = chunkOff[blockIdx.x] + sm[t] - own;
        offs[i] = o;
        cursor[i] = o;
    }
}

__global__ void fill_kernel(const int* __restrict__ ei, int* __restrict__ cursor,
                            int* __restrict__ srcl, int E) {
    int e = blockIdx.x * blockDim.x + threadIdx.x;
    if (e >= E) return;
    int s = ei[e];
    int d = ei[(size_t)E + e];
    int pos = atomicAdd(&cursor[d], 1);
    srcl[pos] = s;
}

// ---------------- W transpose: Wt[n][k] = f16(W[k][n]) ----------------
__global__ void transpose_w_kernel(const float* __restrict__ W, unsigned short* __restrict__ Wt) {
    __shared__ float tile[32][33];
    int mat = blockIdx.x >> 6, t = blockIdx.x & 63;
    int kt = (t >> 3) * 32, nt = (t & 7) * 32;
    const float* Wm = W + (size_t)mat * HH * HH;
    unsigned short* Wtm = Wt + (size_t)mat * HH * HH;
    int lx = threadIdx.x & 31, ly = threadIdx.x >> 5;
#pragma unroll
    for (int yy = 0; yy < 32; yy += 8)
        tile[ly + yy][lx] = Wm[(size_t)(kt + ly + yy) * HH + nt + lx];
    __syncthreads();
#pragma unroll
    for (int yy = 0; yy < 32; yy += 8)
        Wtm[(size_t)(nt + ly + yy) * HH + kt + lx] = f2h(tile[lx][ly + yy]);
}

// ---------------- stats init ----------------
__global__ void init_stats_kernel(float* __restrict__ stats) {
    int i = blockIdx.x * blockDim.x + threadIdx.x;
    int slot = i >> 9;
    if (slot < NSLOT) stats[(size_t)slot * 4 * HH + (i & 511)] = 0.f;
}

// gather one row (16B/lane, 8 channels), transform, accumulate
__device__ __forceinline__ void gath_acc(const unsigned short* __restrict__ h, int row, int c,
                                         const float* sc, const float* sh, bool apply, float* a) {
    uint4 raw = *(const uint4*)&h[(size_t)row * HH + c];
    unsigned short hx[8];
    *(uint4*)hx = raw;
#pragma unroll
    for (int t = 0; t < 8; ++t) {
        float v = h2f(hx[t]);
        if (apply) v = fmaxf(v * sc[t] + sh[t], 0.f);
        a[t] += v;
    }
}

// ---------------- fused aggregation: z[n] = t(x[n]) + sum t(x[src_j]) ----------------
// 1 node/wave; 32 lanes x 16B cover a row; halves (lane>>5) take even/odd edges;
// 2x inner unroll -> 4 gathers in flight per wave. t() = BN+relu when stats!=null.
__global__ __launch_bounds__(256) void aggregate_fused_kernel(
        const unsigned short* __restrict__ h,
        const int* __restrict__ offs, const int* __restrict__ srcl,
        const float* __restrict__ stats, const float* __restrict__ gv,
        const float* __restrict__ bv, float invM,
        unsigned short* __restrict__ z, int N) {
    int n = blockIdx.x * 4 + (threadIdx.x >> 6);
    int l = threadIdx.x & 63;
    if (n >= N) return;
    int half = l >> 5;
    int c = (l & 31) * 8;
    const bool apply = (stats != nullptr);
    float sc[8], sh[8];
#pragma unroll
    for (int t = 0; t < 8; ++t) {
        if (apply) bn_derive(stats, gv, bv, invM, c + t, sc[t], sh[t]);
        else { sc[t] = 1.f; sh[t] = 0.f; }
    }
    float a[8] = {0.f, 0.f, 0.f, 0.f, 0.f, 0.f, 0.f, 0.f};
    float b2[8] = {0.f, 0.f, 0.f, 0.f, 0.f, 0.f, 0.f, 0.f};

    if (half == 0) gath_acc(h, n, c, sc, sh, apply, a);   // self term
    int s1 = offs[n + 1];
    int j = offs[n] + half;
    for (; j + 2 < s1; j += 4) {
        int ra = srcl[j];
        int rb = srcl[j + 2];
        gath_acc(h, ra, c, sc, sh, apply, a);
        gath_acc(h, rb, c, sc, sh, apply, b2);
    }
    if (j < s1) gath_acc(h, srcl[j], c, sc, sh, apply, a);

#pragma unroll
    for (int t = 0; t < 8; ++t) a[t] += b2[t];
#pragma unroll
    for (int t = 0; t < 8; ++t) a[t] += __shfl_xor(a[t], 32);
    if (half == 0) {
        unsigned short o[8];
#pragma unroll
        for (int t = 0; t < 8; ++t) o[t] = f2h(a[t]);
        *(uint4*)&z[(size_t)n * HH + c] = *(uint4*)o;
    }
}

// ---------------- f16 MFMA GEMM + fused BN partial stats ----------------
// Tile 128x128, BK=64, 4 waves (2x2). LDS staging [128][64]f16 x2 with 16B-granule
// XOR swizzle (g ^= row&7); staging pre-swizzles the GLOBAL source (rule #21).
// Epilogue stages C through LDS (stride 136) -> coalesced dwordx4 stores.
__global__ __launch_bounds__(256) void mfma_gemm_kernel(const unsigned short* __restrict__ A,
                                                        const unsigned short* __restrict__ Wt,
                                                        const float* __restrict__ bias,
                                                        unsigned short* __restrict__ C,
                                                        float* __restrict__ stats,
                                                        int M) {
    __shared__ unsigned short sm[128 * 136];   // staging: [0,16384); epilogue: whole
    unsigned short* As = sm;
    unsigned short* Bs = sm + 128 * 64;
    int tid = threadIdx.x;
    int w = tid >> 6, l = tid & 63;
    int wr = w >> 1, wc = w & 1;
    int row0 = blockIdx.x * 128;
    int col0 = blockIdx.y * 128;
    int g = (l & 7) ^ (l >> 3);      // pre-swizzled source granule
    int srow = w * 8 + (l >> 3);

    f32x4 acc[4][4] = {};

    const unsigned short* AB = A + (size_t)row0 * HH;
    const unsigned short* WB = Wt + (size_t)col0 * HH;

    for (int k0 = 0; k0 < 256; k0 += 64) {
#pragma unroll
        for (int r = 0; r < 4; ++r) {
            int row = r * 32 + srow;
            size_t go = (size_t)row * HH + k0 + g * 8;
            int lo = (r * 32 + w * 8) * 64;
            gload16(AB + go, &As[lo]);
            gload16(WB + go, &Bs[lo]);
        }
        __syncthreads();
#pragma unroll
        for (int kh = 0; kh < 2; ++kh) {
            f16x8 af[4], bf[4];
#pragma unroll
            for (int m = 0; m < 4; ++m) {
                int rr = wr * 64 + m * 16 + (l & 15);
                int gs = (kh * 4 + (l >> 4)) ^ (rr & 7);
                af[m] = *(const f16x8*)&As[rr * 64 + gs * 8];
            }
#pragma unroll
            for (int n = 0; n < 4; ++n) {
                int rr = wc * 64 + n * 16 + (l & 15);
                int gs = (kh * 4 + (l >> 4)) ^ (rr & 7);
                bf[n] = *(const f16x8*)&Bs[rr * 64 + gs * 8];
            }
#pragma unroll
            for (int m = 0; m < 4; ++m)
#pragma unroll
                for (int n = 0; n < 4; ++n)
                    acc[m][n] = __builtin_amdgcn_mfma_f32_16x16x32_f16(af[m], bf[n], acc[m][n], 0, 0, 0);
        }
        __syncthreads();
    }

    // epilogue: bias + stats (register-side) + C-tile via LDS, coalesced stores
    int mvalid = M - row0;
#pragma unroll
    for (int n = 0; n < 4; ++n) {
        int colr = wc * 64 + n * 16 + (l & 15);
        float bvv = bias[col0 + colr];
        float s = 0.f, s2 = 0.f;
#pragma unroll
        for (int m = 0; m < 4; ++m) {
            int rb = wr * 64 + m * 16 + (l >> 4) * 4;
#pragma unroll
            for (int r = 0; r < 4; ++r) {
                float v = acc[m][n][r] + bvv;
                sm[(rb + r) * 136 + colr] = f2h(v);
                if (rb + r < mvalid) { s += v; s2 += v * v; }
            }
        }
        s += __shfl_xor(s, 16);   s += __shfl_xor(s, 32);
        s2 += __shfl_xor(s2, 16); s2 += __shfl_xor(s2, 32);
        if ((l >> 4) == 0) {
            atomicAdd(&stats[col0 + colr], s);
            atomicAdd(&stats[HH + col0 + colr], s2);
        }
    }
    __syncthreads();
#pragma unroll
    for (int i = 0; i < 8; ++i) {
        int ci = i * 256 + tid;          // 0..2047 chunk id
        int row = ci >> 4;
        int cq = (ci & 15) * 8;
        if (row0 + row < M) {
            uint4 v = *(const uint4*)&sm[row * 136 + cq];
            *(uint4*)&C[(size_t)(row0 + row) * HH + col0 + cq] = v;
        }
    }
}

// ---------------- BN helpers ----------------
__global__ void bn_stats_kernel(const float* __restrict__ X, int M, float* __restrict__ stats) {
    int c = threadIdx.x;
    int r0 = blockIdx.x * 128;
    int r1 = min(r0 + 128, M);
    float s = 0.f, s2 = 0.f;
    for (int r = r0; r < r1; ++r) {
        float v = X[(size_t)r * HH + c];
        s += v;
        s2 += v * v;
    }
    atomicAdd(&stats[c], s);
    atomicAdd(&stats[HH + c], s2);
}

__global__ void bn_finalize_kernel(float* __restrict__ stats, const float* __restrict__ g,
                                   const float* __restrict__ b, float invM) {
    int c = threadIdx.x;
    float sc, sh;
    bn_derive(stats, g, b, invM, c, sc, sh);
    stats[2 * HH + c] = sc;
    stats[3 * HH + c] = sh;
}

// f16 in-place: x = relu(x*sc + sh), 8 elems/thread; finalize inlined
__global__ void bn_apply_relu_f16_kernel(unsigned short* __restrict__ X, int n8,
                                         const float* __restrict__ stats,
                                         const float* __restrict__ gv,
                                         const float* __restrict__ bv, float invM) {
    int i = blockIdx.x * blockDim.x + threadIdx.x;
    int stride = gridDim.x * blockDim.x;
    for (; i < n8; i += stride) {
        int c0 = (i & 31) * 8;
        uint4 raw = *(const uint4*)&X[(size_t)i * 8];
        unsigned short hx[8], out[8];
        *(uint4*)hx = raw;
#pragma unroll
        for (int t = 0; t < 8; ++t) {
            float sc, sh;
            bn_derive(stats, gv, bv, invM, c0 + t, sc, sh);
            float y = fmaxf(h2f(hx[t]) * sc + sh, 0.f);
            out[t] = f2h(y);
        }
        *(uint4*)&X[(size_t)i * 8] = *(uint4*)out;
    }
}

// classifier-only f32 in-place apply
__global__ void bn_apply_relu_kernel(float* __restrict__ X, int n4, const float* __restrict__ stats) {
    int i = blockIdx.x * blockDim.x + threadIdx.x;
    int stride = gridDim.x * blockDim.x;
    for (; i < n4; i += stride) {
        int c4 = (i & 63) * 4;
        float4 v = ((float4*)X)[i];
        float4 sc = *(const float4*)&stats[2 * HH + c4];
        float4 sh = *(const float4*)&stats[3 * HH + c4];
        v.x = fmaxf(v.x * sc.x + sh.x, 0.f);
        v.y = fmaxf(v.y * sc.y + sh.y, 0.f);
        v.z = fmaxf(v.z * sc.z + sh.z, 0.f);
        v.w = fmaxf(v.w * sc.w + sh.w, 0.f);
        ((float4*)X)[i] = v;
    }
}

// ---------------- f32 GEMM (classifier only) ----------------
__global__ __launch_bounds__(256) void gemm_kernel(const float* __restrict__ A,
                                                   const float* __restrict__ W,
                                                   const float* __restrict__ bias,
                                                   float* __restrict__ C,
                                                   int M, int ldw) {
    __shared__ float Asm[64][33];
    __shared__ float Wsm[32][64];
    int tid = threadIdx.x;
    int tx = tid & 15, ty = tid >> 4;
    int row0 = blockIdx.x * 64;
    int col0 = blockIdx.y * 64;
    float acc[4][4] = {};

    for (int k0 = 0; k0 < 256; k0 += 32) {
#pragma unroll
        for (int t = 0; t < 2; ++t) {
            int s = tid + t * 256;
            int m = s >> 3;
            int kq = (s & 7) * 4;
            float4 v = make_float4(0.f, 0.f, 0.f, 0.f);
            if (row0 + m < M) v = *(const float4*)&A[(size_t)(row0 + m) * 256 + k0 + kq];
            Asm[m][kq + 0] = v.x; Asm[m][kq + 1] = v.y; Asm[m][kq + 2] = v.z; Asm[m][kq + 3] = v.w;
        }
#pragma unroll
        for (int t = 0; t < 2; ++t) {
            int s = tid + t * 256;
            int kk = s >> 4;
            int cq = (s & 15) * 4;
            *(float4*)&Wsm[kk][cq] = *(const float4*)&W[(size_t)(k0 + kk) * ldw + col0 + cq];
        }
        __syncthreads();
#pragma unroll
        for (int kk = 0; kk < 32; ++kk) {
            float a0 = Asm[ty * 4 + 0][kk];
            float a1 = Asm[ty * 4 + 1][kk];
            float a2 = Asm[ty * 4 + 2][kk];
            float a3 = Asm[ty * 4 + 3][kk];
            float4 wv = *(const float4*)&Wsm[kk][tx * 4];
            acc[0][0] += a0 * wv.x; acc[0][1] += a0 * wv.y; acc[0][2] += a0 * wv.z; acc[0][3] += a0 * wv.w;
            acc[1][0] += a1 * wv.x; acc[1][1] += a1 * wv.y; acc[1][2] += a1 * wv.z; acc[1][3] += a1 * wv.w;
            acc[2][0] += a2 * wv.x; acc[2][1] += a2 * wv.y; acc[2][2] += a2 * wv.z; acc[2][3] += a2 * wv.w;
            acc[3][0] += a3 * wv.x; acc[3][1] += a3 * wv.y; acc[3][2] += a3 * wv.z; acc[3][3] += a3 * wv.w;
        }
        __syncthreads();
    }

    float4 bvv = *(const float4*)&bias[col0 + tx * 4];
#pragma unroll
    for (int j = 0; j < 4; ++j) {
        int row = row0 + ty * 4 + j;
        if (row < M) {
            float4 o = make_float4(acc[j][0] + bvv.x, acc[j][1] + bvv.y,
                                   acc[j][2] + bvv.z, acc[j][3] + bvv.w);
            *(float4*)&C[(size_t)row * ldw + col0 + tx * 4] = o;
        }
    }
}

// ---------------- fused mean pool: pooled = mean relu(bn(z2_last)) ----------------
__device__ __forceinline__ int lbound(const int* a, int n, int v) {
    int lo = 0, hi = n;
    while (lo < hi) {
        int mid = (lo + hi) >> 1;
        if (a[mid] < v) lo = mid + 1; else hi = mid;
    }
    return lo;
}

__global__ void pool_fused_kernel(const unsigned short* __restrict__ Hm,
                                  const int* __restrict__ batch,
                                  const float* __restrict__ stats,
                                  const float* __restrict__ gv,
                                  const float* __restrict__ bv, float invM,
                                  int N, float* __restrict__ pooled) {
    int g = blockIdx.x;
    int c = threadIdx.x;
    int s = lbound(batch, N, g);
    int e = lbound(batch, N, g + 1);
    float sc, sh;
    bn_derive(stats, gv, bv, invM, c, sc, sh);
    float acc = 0.f;
    for (int r = s; r < e; ++r)
        acc += fmaxf(h2f(Hm[(size_t)r * HH + c]) * sc + sh, 0.f);
    pooled[(size_t)g * HH + c] = acc / (float)max(e - s, 1);
}

// ---------------- launch ----------------
extern "C" void kernel_launch(void* const* d_in, const int* in_sizes, int n_in,
                              void* d_out, int out_size, void* d_ws, size_t ws_size,
                              hipStream_t stream) {
    const float* x_atom = (const float*)d_in[0];
    const float* x_pe   = (const float*)d_in[1];
    const int* ei       = (const int*)d_in[2];
    const int* batch    = (const int*)d_in[3];
    const float* ae_w = (const float*)d_in[4];
    const float* ae_b = (const float*)d_in[5];
    const float* pe_w = (const float*)d_in[6];
    const float* pe_b = (const float*)d_in[7];
    const float* w1  = (const float*)d_in[8];
    const float* b1  = (const float*)d_in[9];
    const float* g1  = (const float*)d_in[10];
    const float* be1 = (const float*)d_in[11];
    const float* w2  = (const float*)d_in[12];
    const float* b2  = (const float*)d_in[13];
    const float* bng = (const float*)d_in[14];
    const float* bnb = (const float*)d_in[15];
    const float* cl1_w = (const float*)d_in[16];
    const float* cl1_b = (const float*)d_in[17];
    const float* clg = (const float*)d_in[18];
    const float* clb = (const float*)d_in[19];
    const float* cl2_w = (const float*)d_in[20];
    const float* cl2_b = (const float*)d_in[21];

    const int N = in_sizes[3];
    const int E = in_sizes[2] / 2;
    const int T = in_sizes[21];
    const int B = out_size / T;
    const int Lnum = in_sizes[9] / HH;
    const int nc = cdiv(N, CHUNK);
    const int Npad = cdiv(N, 128) * 128;
    const size_t P = (size_t)Npad * HH;

    unsigned short* X = (unsigned short*)d_ws;
    unsigned short* Y = X + P;
    unsigned short* wt1 = Y + P;                        // L*HH*HH f16
    unsigned short* wt2 = wt1 + (size_t)Lnum * HH * HH;
    float* stats = (float*)(wt2 + (size_t)Lnum * HH * HH);   // NSLOT x 4*HH
    float* pooled = stats + (size_t)NSLOT * 4 * HH;
    float* zc = pooled + (size_t)B * HH;
    int* deg = (int*)(zc + (size_t)B * HH);
    int* offs = deg + N;
    int* cursor = offs + N + 1;
    int* chunkSum = cursor + N;
    int* chunkOff = chunkSum + 256;
    int* srcl = chunkOff + 256;

    const int n8 = N * (HH / 8);
    const int BH4 = B * (HH / 4);
    const float invN = 1.f / (float)N;

    // ---- CSR build ----
    zero_int_kernel<<<cdiv(N, 256), 256, 0, stream>>>(deg, N);
    hist_kernel<<<cdiv(E, 256), 256, 0, stream>>>(ei, deg, E);
    ps1_kernel<<<nc, CHUNK, 0, stream>>>(deg, chunkSum, N);
    ps2_kernel<<<1, CHUNK, 0, stream>>>(chunkSum, chunkOff, nc, offs, N, E);
    ps3_kernel<<<nc, CHUNK, 0, stream>>>(deg, chunkOff, offs, cursor, N);
    fill_kernel<<<cdiv(E, 256), 256, 0, stream>>>(ei, cursor, srcl, E);

    // ---- weight transpose (f32 -> f16, [k][n] -> [n][k]) ----
    transpose_w_kernel<<<Lnum * 64, 256, 0, stream>>>(w1, wt1);
    transpose_w_kernel<<<Lnum * 64, 256, 0, stream>>>(w2, wt2);

    // ---- stats init (all slots, once) ----
    init_stats_kernel<<<cdiv(NSLOT * 512, 256), 256, 0, stream>>>(stats);

    // ---- embed ----
    embed_kernel<<<N, HH, 0, stream>>>(x_atom, x_pe, ae_w, ae_b, pe_w, pe_b, X, N);

    dim3 mf_grid(cdiv(N, 128), 2);
    int apply_blocks = min(2048, cdiv(n8, 256));

    unsigned short *in = X, *ot = Y;

    for (int i = 0; i < Lnum; ++i) {
        float* slot1 = stats + (size_t)(2 * i) * 4 * HH;
        float* slot2 = stats + (size_t)(2 * i + 1) * 4 * HH;
        const float* aggStats = (i == 0) ? nullptr : stats + (size_t)(2 * i - 1) * 4 * HH;
        const float* aggG = (i == 0) ? nullptr : bng + (size_t)(i - 1) * HH;
        const float* aggB = (i == 0) ? nullptr : bnb + (size_t)(i - 1) * HH;

        // z = t(in) + gather-sum t(in[src]) : in -> ot
        aggregate_fused_kernel<<<cdiv(N, 4), 256, 0, stream>>>(in, offs, srcl,
                                                               aggStats, aggG, aggB, invN, ot, N);

        // z1 = z @ w1 + b1 : ot -> in ; inner BN+relu in place
        mfma_gemm_kernel<<<mf_grid, 256, 0, stream>>>(ot, wt1 + (size_t)i * HH * HH,
                                                      b1 + (size_t)i * HH, in, slot1, N);
        bn_apply_relu_f16_kernel<<<apply_blocks, 256, 0, stream>>>(in, n8, slot1,
                                                                   g1 + (size_t)i * HH,
                                                                   be1 + (size_t)i * HH, invN);

        // z2 = a1 @ w2 + b2 : in -> ot (raw; outer BN fused into next consumer)
        mfma_gemm_kernel<<<mf_grid, 256, 0, stream>>>(in, wt2 + (size_t)i * HH * HH,
                                                      b2 + (size_t)i * HH, ot, slot2, N);

        unsigned short* t = in; in = ot; ot = t;
    }

    // ---- fused mean pool (applies last outer BN+relu) ----
    pool_fused_kernel<<<B, HH, 0, stream>>>(in, batch,
                                            stats + (size_t)(2 * Lnum - 1) * 4 * HH,
                                            bng + (size_t)(Lnum - 1) * HH,
                                            bnb + (size_t)(Lnum - 1) * HH, invN, N, pooled);

    // ---- classifier (f32 path, slot 10) ----
    float* slotC = stats + (size_t)10 * 4 * HH;
    dim3 cls_grid1(cdiv(B, 64), HH / 64);
    gemm_kernel<<<cls_grid1, 256, 0, stream>>>(pooled, cl1_w, cl1_b, zc, B, HH);
    bn_stats_kernel<<<cdiv(B, 128), HH, 0, stream>>>(zc, B, slotC);
    bn_finalize_kernel<<<1, HH, 0, stream>>>(slotC, clg, clb, 1.f / B);
    bn_apply_relu_kernel<<<min(2048, cdiv(BH4, 256)), 256, 0, stream>>>(zc, BH4, slotC);

    dim3 cls_grid2(cdiv(B, 64), T / 64);
    gemm_kernel<<<cls_grid2, 256, 0, stream>>>(zc, cl2_w, cl2_b, (float*)d_out, B, T);
}

// Round 9
// 1067.216 us; speedup vs baseline: 1.4675x; 1.4675x over previous
//
#include <hip/hip_runtime.h>
#include <hip/hip_bf16.h>
#include <stdint.h>

#define HH 256
#define BN_EPS 1e-5f
#define CHUNK 256
#define NSLOT 12   // stats slots: layer i -> 2i (inner), 2i+1 (outer); classifier -> 10

static inline int cdiv(int a, int b) { return (a + b - 1) / b; }

typedef _Float16 f16x8 __attribute__((ext_vector_type(8)));
typedef __attribute__((ext_vector_type(4))) float f32x4;

__device__ __forceinline__ unsigned short f2h(float f) {
    _Float16 h = (_Float16)f;            // v_cvt_f16_f32, RNE
    unsigned short u;
    __builtin_memcpy(&u, &h, 2);
    return u;
}
__device__ __forceinline__ float h2f(unsigned short u) {
    _Float16 h;
    __builtin_memcpy(&h, &u, 2);
    return (float)h;
}

__device__ __forceinline__ void gload16(const void* g, void* lds) {
    __builtin_amdgcn_global_load_lds((const __attribute__((address_space(1))) unsigned int*)g,
                                     (__attribute__((address_space(3))) unsigned int*)lds, 16, 0, 0);
}

// derive BN scale/shift for one channel from raw sums
__device__ __forceinline__ void bn_derive(const float* __restrict__ stats, const float* __restrict__ g,
                                          const float* __restrict__ b, float invM, int c,
                                          float& sc, float& sh) {
    float mu = stats[c] * invM;
    float var = stats[HH + c] * invM - mu * mu;
    float rstd = rsqrtf(var + BN_EPS);
    sc = rstd * g[c];
    sh = b[c] - mu * sc;
}

// ---------------- embed -> f16 ----------------
__global__ void embed_kernel(const float* __restrict__ xa, const float* __restrict__ xp,
                             const float* __restrict__ aw, const float* __restrict__ ab,
                             const float* __restrict__ pw, const float* __restrict__ pb,
                             unsigned short* __restrict__ h, int N) {
    int n = blockIdx.x;
    int c = threadIdx.x;
    if (n >= N) return;
    float acc = ab[c] + pb[c];
#pragma unroll
    for (int k = 0; k < 9; ++k) acc += xa[n * 9 + k] * aw[k * HH + c];
#pragma unroll
    for (int k = 0; k < 8; ++k) acc += xp[n * 8 + k] * pw[k * HH + c];
    h[(size_t)n * HH + c] = f2h(acc);
}

// ---------------- CSR build ----------------
__global__ void zero_int_kernel(int* __restrict__ p, int n) {
    int i = blockIdx.x * blockDim.x + threadIdx.x;
    if (i < n) p[i] = 0;
}

__global__ void hist_kernel(const int* __restrict__ ei, int* __restrict__ deg, int E) {
    int e = blockIdx.x * blockDim.x + threadIdx.x;
    if (e < E) atomicAdd(&deg[ei[(size_t)E + e]], 1);
}

__global__ void ps1_kernel(const int* __restrict__ deg, int* __restrict__ chunkSum, int N) {
    __shared__ int sm[CHUNK];
    int i = blockIdx.x * CHUNK + threadIdx.x;
    sm[threadIdx.x] = (i < N) ? deg[i] : 0;
    __syncthreads();
    for (int off = CHUNK / 2; off > 0; off >>= 1) {
        if (threadIdx.x < off) sm[threadIdx.x] += sm[threadIdx.x + off];
        __syncthreads();
    }
    if (threadIdx.x == 0) chunkSum[blockIdx.x] = sm[0];
}

__global__ void ps2_kernel(const int* __restrict__ chunkSum, int* __restrict__ chunkOff,
                           int nc, int* __restrict__ offs, int N, int E) {
    __shared__ int sm[CHUNK];
    int t = threadIdx.x;
    int own = (t < nc) ? chunkSum[t] : 0;
    sm[t] = own;
    for (int off = 1; off < CHUNK; off <<= 1) {
        __syncthreads();
        int v = (t >= off) ? sm[t - off] : 0;
        __syncthreads();
        sm[t] += v;
    }
    if (t < nc) chunkOff[t] = sm[t] - own;
    if (t == 0) offs[N] = E;
}

__global__ void ps3_kernel(const int* __restrict__ deg, const int* __restrict__ chunkOff,
                           int* __restrict__ offs, int* __restrict__ cursor, int N) {
    __shared__ int sm[CHUNK];
    int t = threadIdx.x;
    int i = blockIdx.x * CHUNK + t;
    int own = (i < N) ? deg[i] : 0;
    sm[t] = own;
    for (int off = 1; off < CHUNK; off <<= 1) {
        __syncthreads();
        int v = (t >= off) ? sm[t - off] : 0;
        __syncthreads();
        sm[t] += v;
    }
    if (i < N) {
        int o = chunkOff[blockIdx.x] + sm[t] - own;
        offs[i] = o;
        cursor[i] = o;
    }
}

__global__ void fill_kernel(const int* __restrict__ ei, int* __restrict__ cursor,
                            int* __restrict__ srcl, int E) {
    int e = blockIdx.x * blockDim.x + threadIdx.x;
    if (e >= E) return;
    int s = ei[e];
    int d = ei[(size_t)E + e];
    int pos = atomicAdd(&cursor[d], 1);
    srcl[pos] = s;
}

// ---------------- W transpose: Wt[n][k] = f16(W[k][n]) ----------------
__global__ void transpose_w_kernel(const float* __restrict__ W, unsigned short* __restrict__ Wt) {
    __shared__ float tile[32][33];
    int mat = blockIdx.x >> 6, t = blockIdx.x & 63;
    int kt = (t >> 3) * 32, nt = (t & 7) * 32;
    const float* Wm = W + (size_t)mat * HH * HH;
    unsigned short* Wtm = Wt + (size_t)mat * HH * HH;
    int lx = threadIdx.x & 31, ly = threadIdx.x >> 5;
#pragma unroll
    for (int yy = 0; yy < 32; yy += 8)
        tile[ly + yy][lx] = Wm[(size_t)(kt + ly + yy) * HH + nt + lx];
    __syncthreads();
#pragma unroll
    for (int yy = 0; yy < 32; yy += 8)
        Wtm[(size_t)(nt + ly + yy) * HH + kt + lx] = f2h(tile[lx][ly + yy]);
}

// ---------------- stats init ----------------
__global__ void init_stats_kernel(float* __restrict__ stats) {
    int i = blockIdx.x * blockDim.x + threadIdx.x;
    int slot = i >> 9;
    if (slot < NSLOT) stats[(size_t)slot * 4 * HH + (i & 511)] = 0.f;
}

// ---------------- fused aggregation: z[n] = t(x[n]) + sum t(x[src_j]) ----------------
// Proven round-6 structure: 1 node/wave, 64 lanes x ushort4 (8B) per row, uniform j
// across the wave; unrolled to 4 independent edge gathers in flight.
// t() = BN+relu when stats != null (finalize inlined from raw sums).
__global__ __launch_bounds__(256) void aggregate_fused_kernel(
        const unsigned short* __restrict__ h,
        const int* __restrict__ offs, const int* __restrict__ srcl,
        const float* __restrict__ stats, const float* __restrict__ gv,
        const float* __restrict__ bv, float invM,
        unsigned short* __restrict__ z, int N) {
    int n = blockIdx.x * 4 + (threadIdx.x >> 6);
    int l = threadIdx.x & 63;
    if (n >= N) return;
    int c = l * 4;
    const bool apply = (stats != nullptr);
    float sc0 = 1.f, sc1 = 1.f, sc2 = 1.f, sc3 = 1.f;
    float sh0 = 0.f, sh1 = 0.f, sh2 = 0.f, sh3 = 0.f;
    if (apply) {
        bn_derive(stats, gv, bv, invM, c + 0, sc0, sh0);
        bn_derive(stats, gv, bv, invM, c + 1, sc1, sh1);
        bn_derive(stats, gv, bv, invM, c + 2, sc2, sh2);
        bn_derive(stats, gv, bv, invM, c + 3, sc3, sh3);
    }

#define LOADT(row, r0, r1, r2, r3)                                      \
    {                                                                   \
        ushort4 v_ = *(const ushort4*)&h[(size_t)(row) * HH + c];       \
        r0 = h2f(v_.x); r1 = h2f(v_.y); r2 = h2f(v_.z); r3 = h2f(v_.w); \
        if (apply) {                                                    \
            r0 = fmaxf(r0 * sc0 + sh0, 0.f);                            \
            r1 = fmaxf(r1 * sc1 + sh1, 0.f);                            \
            r2 = fmaxf(r2 * sc2 + sh2, 0.f);                            \
            r3 = fmaxf(r3 * sc3 + sh3, 0.f);                            \
        }                                                               \
    }

    float a0, a1, a2, a3;
    LOADT(n, a0, a1, a2, a3);                   // self term
    int s0 = offs[n], s1 = offs[n + 1];
    int j = s0;
    for (; j + 4 <= s1; j += 4) {
        int r0 = srcl[j], r1 = srcl[j + 1], r2 = srcl[j + 2], r3 = srcl[j + 3];
        float t0, t1, t2, t3, u0, u1, u2, u3;
        float p0, p1, p2, p3, q0, q1, q2, q3;
        LOADT(r0, t0, t1, t2, t3);
        LOADT(r1, u0, u1, u2, u3);
        LOADT(r2, p0, p1, p2, p3);
        LOADT(r3, q0, q1, q2, q3);
        a0 += (t0 + u0) + (p0 + q0);
        a1 += (t1 + u1) + (p1 + q1);
        a2 += (t2 + u2) + (p2 + q2);
        a3 += (t3 + u3) + (p3 + q3);
    }
    for (; j < s1; ++j) {
        float t0, t1, t2, t3;
        LOADT(srcl[j], t0, t1, t2, t3);
        a0 += t0; a1 += t1; a2 += t2; a3 += t3;
    }
#undef LOADT
    ushort4 o;
    o.x = f2h(a0); o.y = f2h(a1); o.z = f2h(a2); o.w = f2h(a3);
    *(ushort4*)&z[(size_t)n * HH + c] = o;
}

// ---------------- f16 MFMA GEMM + fused BN partial stats ----------------
// Tile 128x128, BK=64, 4 waves (2x2). LDS staging [128][64]f16 x2 with 16B-granule
// XOR swizzle (g ^= row&7); staging pre-swizzles the GLOBAL source (rule #21).
// Epilogue stages C through LDS (stride 136) -> coalesced dwordx4 stores.
__global__ __launch_bounds__(256) void mfma_gemm_kernel(const unsigned short* __restrict__ A,
                                                        const unsigned short* __restrict__ Wt,
                                                        const float* __restrict__ bias,
                                                        unsigned short* __restrict__ C,
                                                        float* __restrict__ stats,
                                                        int M) {
    __shared__ unsigned short sm[128 * 136];   // staging: [0,16384); epilogue: whole
    unsigned short* As = sm;
    unsigned short* Bs = sm + 128 * 64;
    int tid = threadIdx.x;
    int w = tid >> 6, l = tid & 63;
    int wr = w >> 1, wc = w & 1;
    int row0 = blockIdx.x * 128;
    int col0 = blockIdx.y * 128;
    int g = (l & 7) ^ (l >> 3);      // pre-swizzled source granule
    int srow = w * 8 + (l >> 3);

    f32x4 acc[4][4] = {};

    const unsigned short* AB = A + (size_t)row0 * HH;
    const unsigned short* WB = Wt + (size_t)col0 * HH;

    for (int k0 = 0; k0 < 256; k0 += 64) {
#pragma unroll
        for (int r = 0; r < 4; ++r) {
            int row = r * 32 + srow;
            size_t go = (size_t)row * HH + k0 + g * 8;
            int lo = (r * 32 + w * 8) * 64;
            gload16(AB + go, &As[lo]);
            gload16(WB + go, &Bs[lo]);
        }
        __syncthreads();
#pragma unroll
        for (int kh = 0; kh < 2; ++kh) {
            f16x8 af[4], bf[4];
#pragma unroll
            for (int m = 0; m < 4; ++m) {
                int rr = wr * 64 + m * 16 + (l & 15);
                int gs = (kh * 4 + (l >> 4)) ^ (rr & 7);
                af[m] = *(const f16x8*)&As[rr * 64 + gs * 8];
            }
#pragma unroll
            for (int n = 0; n < 4; ++n) {
                int rr = wc * 64 + n * 16 + (l & 15);
                int gs = (kh * 4 + (l >> 4)) ^ (rr & 7);
                bf[n] = *(const f16x8*)&Bs[rr * 64 + gs * 8];
            }
#pragma unroll
            for (int m = 0; m < 4; ++m)
#pragma unroll
                for (int n = 0; n < 4; ++n)
                    acc[m][n] = __builtin_amdgcn_mfma_f32_16x16x32_f16(af[m], bf[n], acc[m][n], 0, 0, 0);
        }
        __syncthreads();
    }

    // epilogue: bias + stats (register-side) + C-tile via LDS, coalesced stores
    int mvalid = M - row0;
#pragma unroll
    for (int n = 0; n < 4; ++n) {
        int colr = wc * 64 + n * 16 + (l & 15);
        float bvv = bias[col0 + colr];
        float s = 0.f, s2 = 0.f;
#pragma unroll
        for (int m = 0; m < 4; ++m) {
            int rb = wr * 64 + m * 16 + (l >> 4) * 4;
#pragma unroll
            for (int r = 0; r < 4; ++r) {
                float v = acc[m][n][r] + bvv;
                sm[(rb + r) * 136 + colr] = f2h(v);
                if (rb + r < mvalid) { s += v; s2 += v * v; }
            }
        }
        s += __shfl_xor(s, 16);   s += __shfl_xor(s, 32);
        s2 += __shfl_xor(s2, 16); s2 += __shfl_xor(s2, 32);
        if ((l >> 4) == 0) {
            atomicAdd(&stats[col0 + colr], s);
            atomicAdd(&stats[HH + col0 + colr], s2);
        }
    }
    __syncthreads();
#pragma unroll
    for (int i = 0; i < 8; ++i) {
        int ci = i * 256 + tid;          // 0..2047 chunk id
        int row = ci >> 4;
        int cq = (ci & 15) * 8;
        if (row0 + row < M) {
            uint4 v = *(const uint4*)&sm[row * 136 + cq];
            *(uint4*)&C[(size_t)(row0 + row) * HH + col0 + cq] = v;
        }
    }
}

// ---------------- BN helpers ----------------
__global__ void bn_stats_kernel(const float* __restrict__ X, int M, float* __restrict__ stats) {
    int c = threadIdx.x;
    int r0 = blockIdx.x * 128;
    int r1 = min(r0 + 128, M);
    float s = 0.f, s2 = 0.f;
    for (int r = r0; r < r1; ++r) {
        float v = X[(size_t)r * HH + c];
        s += v;
        s2 += v * v;
    }
    atomicAdd(&stats[c], s);
    atomicAdd(&stats[HH + c], s2);
}

__global__ void bn_finalize_kernel(float* __restrict__ stats, const float* __restrict__ g,
                                   const float* __restrict__ b, float invM) {
    int c = threadIdx.x;
    float sc, sh;
    bn_derive(stats, g, b, invM, c, sc, sh);
    stats[2 * HH + c] = sc;
    stats[3 * HH + c] = sh;
}

// f16 in-place: x = relu(x*sc + sh), 8 elems/thread; finalize inlined
__global__ void bn_apply_relu_f16_kernel(unsigned short* __restrict__ X, int n8,
                                         const float* __restrict__ stats,
                                         const float* __restrict__ gv,
                                         const float* __restrict__ bv, float invM) {
    int i = blockIdx.x * blockDim.x + threadIdx.x;
    int stride = gridDim.x * blockDim.x;
    for (; i < n8; i += stride) {
        int c0 = (i & 31) * 8;
        uint4 raw = *(const uint4*)&X[(size_t)i * 8];
        unsigned short hx[8], out[8];
        *(uint4*)hx = raw;
#pragma unroll
        for (int t = 0; t < 8; ++t) {
            float sc, sh;
            bn_derive(stats, gv, bv, invM, c0 + t, sc, sh);
            float y = fmaxf(h2f(hx[t]) * sc + sh, 0.f);
            out[t] = f2h(y);
        }
        *(uint4*)&X[(size_t)i * 8] = *(uint4*)out;
    }
}

// classifier-only f32 in-place apply
__global__ void bn_apply_relu_kernel(float* __restrict__ X, int n4, const float* __restrict__ stats) {
    int i = blockIdx.x * blockDim.x + threadIdx.x;
    int stride = gridDim.x * blockDim.x;
    for (; i < n4; i += stride) {
        int c4 = (i & 63) * 4;
        float4 v = ((float4*)X)[i];
        float4 sc = *(const float4*)&stats[2 * HH + c4];
        float4 sh = *(const float4*)&stats[3 * HH + c4];
        v.x = fmaxf(v.x * sc.x + sh.x, 0.f);
        v.y = fmaxf(v.y * sc.y + sh.y, 0.f);
        v.z = fmaxf(v.z * sc.z + sh.z, 0.f);
        v.w = fmaxf(v.w * sc.w + sh.w, 0.f);
        ((float4*)X)[i] = v;
    }
}

// ---------------- f32 GEMM (classifier only) ----------------
__global__ __launch_bounds__(256) void gemm_kernel(const float* __restrict__ A,
                                                   const float* __restrict__ W,
                                                   const float* __restrict__ bias,
                                                   float* __restrict__ C,
                                                   int M, int ldw) {
    __shared__ float Asm[64][33];
    __shared__ float Wsm[32][64];
    int tid = threadIdx.x;
    int tx = tid & 15, ty = tid >> 4;
    int row0 = blockIdx.x * 64;
    int col0 = blockIdx.y * 64;
    float acc[4][4] = {};

    for (int k0 = 0; k0 < 256; k0 += 32) {
#pragma unroll
        for (int t = 0; t < 2; ++t) {
            int s = tid + t * 256;
            int m = s >> 3;
            int kq = (s & 7) * 4;
            float4 v = make_float4(0.f, 0.f, 0.f, 0.f);
            if (row0 + m < M) v = *(const float4*)&A[(size_t)(row0 + m) * 256 + k0 + kq];
            Asm[m][kq + 0] = v.x; Asm[m][kq + 1] = v.y; Asm[m][kq + 2] = v.z; Asm[m][kq + 3] = v.w;
        }
#pragma unroll
        for (int t = 0; t < 2; ++t) {
            int s = tid + t * 256;
            int kk = s >> 4;
            int cq = (s & 15) * 4;
            *(float4*)&Wsm[kk][cq] = *(const float4*)&W[(size_t)(k0 + kk) * ldw + col0 + cq];
        }
        __syncthreads();
#pragma unroll
        for (int kk = 0; kk < 32; ++kk) {
            float a0 = Asm[ty * 4 + 0][kk];
            float a1 = Asm[ty * 4 + 1][kk];
            float a2 = Asm[ty * 4 + 2][kk];
            float a3 = Asm[ty * 4 + 3][kk];
            float4 wv = *(const float4*)&Wsm[kk][tx * 4];
            acc[0][0] += a0 * wv.x; acc[0][1] += a0 * wv.y; acc[0][2] += a0 * wv.z; acc[0][3] += a0 * wv.w;
            acc[1][0] += a1 * wv.x; acc[1][1] += a1 * wv.y; acc[1][2] += a1 * wv.z; acc[1][3] += a1 * wv.w;
            acc[2][0] += a2 * wv.x; acc[2][1] += a2 * wv.y; acc[2][2] += a2 * wv.z; acc[2][3] += a2 * wv.w;
            acc[3][0] += a3 * wv.x; acc[3][1] += a3 * wv.y; acc[3][2] += a3 * wv.z; acc[3][3] += a3 * wv.w;
        }
        __syncthreads();
    }

    float4 bvv = *(const float4*)&bias[col0 + tx * 4];
#pragma unroll
    for (int j = 0; j < 4; ++j) {
        int row = row0 + ty * 4 + j;
        if (row < M) {
            float4 o = make_float4(acc[j][0] + bvv.x, acc[j][1] + bvv.y,
                                   acc[j][2] + bvv.z, acc[j][3] + bvv.w);
            *(float4*)&C[(size_t)row * ldw + col0 + tx * 4] = o;
        }
    }
}

// ---------------- fused mean pool: pooled = mean relu(bn(z2_last)) ----------------
__device__ __forceinline__ int lbound(const int* a, int n, int v) {
    int lo = 0, hi = n;
    while (lo < hi) {
        int mid = (lo + hi) >> 1;
        if (a[mid] < v) lo = mid + 1; else hi = mid;
    }
    return lo;
}

__global__ void pool_fused_kernel(const unsigned short* __restrict__ Hm,
                                  const int* __restrict__ batch,
                                  const float* __restrict__ stats,
                                  const float* __restrict__ gv,
                                  const float* __restrict__ bv, float invM,
                                  int N, float* __restrict__ pooled) {
    int g = blockIdx.x;
    int c = threadIdx.x;
    int s = lbound(batch, N, g);
    int e = lbound(batch, N, g + 1);
    float sc, sh;
    bn_derive(stats, gv, bv, invM, c, sc, sh);
    float acc = 0.f;
    for (int r = s; r < e; ++r)
        acc += fmaxf(h2f(Hm[(size_t)r * HH + c]) * sc + sh, 0.f);
    pooled[(size_t)g * HH + c] = acc / (float)max(e - s, 1);
}

// ---------------- launch ----------------
extern "C" void kernel_launch(void* const* d_in, const int* in_sizes, int n_in,
                              void* d_out, int out_size, void* d_ws, size_t ws_size,
                              hipStream_t stream) {
    const float* x_atom = (const float*)d_in[0];
    const float* x_pe   = (const float*)d_in[1];
    const int* ei       = (const int*)d_in[2];
    const int* batch    = (const int*)d_in[3];
    const float* ae_w = (const float*)d_in[4];
    const float* ae_b = (const float*)d_in[5];
    const float* pe_w = (const float*)d_in[6];
    const float* pe_b = (const float*)d_in[7];
    const float* w1  = (const float*)d_in[8];
    const float* b1  = (const float*)d_in[9];
    const float* g1  = (const float*)d_in[10];
    const float* be1 = (const float*)d_in[11];
    const float* w2  = (const float*)d_in[12];
    const float* b2  = (const float*)d_in[13];
    const float* bng = (const float*)d_in[14];
    const float* bnb = (const float*)d_in[15];
    const float* cl1_w = (const float*)d_in[16];
    const float* cl1_b = (const float*)d_in[17];
    const float* clg = (const float*)d_in[18];
    const float* clb = (const float*)d_in[19];
    const float* cl2_w = (const float*)d_in[20];
    const float* cl2_b = (const float*)d_in[21];

    const int N = in_sizes[3];
    const int E = in_sizes[2] / 2;
    const int T = in_sizes[21];
    const int B = out_size / T;
    const int Lnum = in_sizes[9] / HH;
    const int nc = cdiv(N, CHUNK);
    const int Npad = cdiv(N, 128) * 128;
    const size_t P = (size_t)Npad * HH;

    unsigned short* X = (unsigned short*)d_ws;
    unsigned short* Y = X + P;
    unsigned short* wt1 = Y + P;                        // L*HH*HH f16
    unsigned short* wt2 = wt1 + (size_t)Lnum * HH * HH;
    float* stats = (float*)(wt2 + (size_t)Lnum * HH * HH);   // NSLOT x 4*HH
    float* pooled = stats + (size_t)NSLOT * 4 * HH;
    float* zc = pooled + (size_t)B * HH;
    int* deg = (int*)(zc + (size_t)B * HH);
    int* offs = deg + N;
    int* cursor = offs + N + 1;
    int* chunkSum = cursor + N;
    int* chunkOff = chunkSum + 256;
    int* srcl = chunkOff + 256;

    const int n8 = N * (HH / 8);
    const int BH4 = B * (HH / 4);
    const float invN = 1.f / (float)N;

    // ---- CSR build ----
    zero_int_kernel<<<cdiv(N, 256), 256, 0, stream>>>(deg, N);
    hist_kernel<<<cdiv(E, 256), 256, 0, stream>>>(ei, deg, E);
    ps1_kernel<<<nc, CHUNK, 0, stream>>>(deg, chunkSum, N);
    ps2_kernel<<<1, CHUNK, 0, stream>>>(chunkSum, chunkOff, nc, offs, N, E);
    ps3_kernel<<<nc, CHUNK, 0, stream>>>(deg, chunkOff, offs, cursor, N);
    fill_kernel<<<cdiv(E, 256), 256, 0, stream>>>(ei, cursor, srcl, E);

    // ---- weight transpose (f32 -> f16, [k][n] -> [n][k]) ----
    transpose_w_kernel<<<Lnum * 64, 256, 0, stream>>>(w1, wt1);
    transpose_w_kernel<<<Lnum * 64, 256, 0, stream>>>(w2, wt2);

    // ---- stats init (all slots, once) ----
    init_stats_kernel<<<cdiv(NSLOT * 512, 256), 256, 0, stream>>>(stats);

    // ---- embed ----
    embed_kernel<<<N, HH, 0, stream>>>(x_atom, x_pe, ae_w, ae_b, pe_w, pe_b, X, N);

    dim3 mf_grid(cdiv(N, 128), 2);
    int apply_blocks = min(2048, cdiv(n8, 256));

    unsigned short *in = X, *ot = Y;

    for (int i = 0; i < Lnum; ++i) {
        float* slot1 = stats + (size_t)(2 * i) * 4 * HH;
        float* slot2 = stats + (size_t)(2 * i + 1) * 4 * HH;
        const float* aggStats = (i == 0) ? nullptr : stats + (size_t)(2 * i - 1) * 4 * HH;
        const float* aggG = (i == 0) ? nullptr : bng + (size_t)(i - 1) * HH;
        const float* aggB = (i == 0) ? nullptr : bnb + (size_t)(i - 1) * HH;

        // z = t(in) + gather-sum t(in[src]) : in -> ot
        aggregate_fused_kernel<<<cdiv(N, 4), 256, 0, stream>>>(in, offs, srcl,
                                                               aggStats, aggG, aggB, invN, ot, N);

        // z1 = z @ w1 + b1 : ot -> in ; inner BN+relu in place
        mfma_gemm_kernel<<<mf_grid, 256, 0, stream>>>(ot, wt1 + (size_t)i * HH * HH,
                                                      b1 + (size_t)i * HH, in, slot1, N);
        bn_apply_relu_f16_kernel<<<apply_blocks, 256, 0, stream>>>(in, n8, slot1,
                                                                   g1 + (size_t)i * HH,
                                                                   be1 + (size_t)i * HH, invN);

        // z2 = a1 @ w2 + b2 : in -> ot (raw; outer BN fused into next consumer)
        mfma_gemm_kernel<<<mf_grid, 256, 0, stream>>>(in, wt2 + (size_t)i * HH * HH,
                                                      b2 + (size_t)i * HH, ot, slot2, N);

        unsigned short* t = in; in = ot; ot = t;
    }

    // ---- fused mean pool (applies last outer BN+relu) ----
    pool_fused_kernel<<<B, HH, 0, stream>>>(in, batch,
                                            stats + (size_t)(2 * Lnum - 1) * 4 * HH,
                                            bng + (size_t)(Lnum - 1) * HH,
                                            bnb + (size_t)(Lnum - 1) * HH, invN, N, pooled);

    // ---- classifier (f32 path, slot 10) ----
    float* slotC = stats + (size_t)10 * 4 * HH;
    dim3 cls_grid1(cdiv(B, 64), HH / 64);
    gemm_kernel<<<cls_grid1, 256, 0, stream>>>(pooled, cl1_w, cl1_b, zc, B, HH);
    bn_stats_kernel<<<cdiv(B, 128), HH, 0, stream>>>(zc, B, slotC);
    bn_finalize_kernel<<<1, HH, 0, stream>>>(slotC, clg, clb, 1.f / B);
    bn_apply_relu_kernel<<<min(2048, cdiv(BH4, 256)), 256, 0, stream>>>(zc, BH4, slotC);

    dim3 cls_grid2(cdiv(B, 64), T / 64);
    gemm_kernel<<<cls_grid2, 256, 0, stream>>>(zc, cl2_w, cl2_b, (float*)d_out, B, T);
}

// Round 10
// 1046.312 us; speedup vs baseline: 1.4968x; 1.0200x over previous
//
#include <hip/hip_runtime.h>
#include <hip/hip_bf16.h>
#include <stdint.h>

#define HH 256
#define BN_EPS 1e-5f
#define CHUNK 256
#define NSLOT 12   // stats slots: layer i -> 2i (inner), 2i+1 (outer); classifier -> 10

static inline int cdiv(int a, int b) { return (a + b - 1) / b; }

typedef _Float16 f16x8 __attribute__((ext_vector_type(8)));
typedef __attribute__((ext_vector_type(4))) float f32x4;

__device__ __forceinline__ unsigned short f2h(float f) {
    _Float16 h = (_Float16)f;            // v_cvt_f16_f32, RNE
    unsigned short u;
    __builtin_memcpy(&u, &h, 2);
    return u;
}
__device__ __forceinline__ float h2f(unsigned short u) {
    _Float16 h;
    __builtin_memcpy(&h, &u, 2);
    return (float)h;
}

__device__ __forceinline__ void gload16(const void* g, void* lds) {
    __builtin_amdgcn_global_load_lds((const __attribute__((address_space(1))) unsigned int*)g,
                                     (__attribute__((address_space(3))) unsigned int*)lds, 16, 0, 0);
}

// derive BN scale/shift for one channel from raw sums
__device__ __forceinline__ void bn_derive(const float* __restrict__ stats, const float* __restrict__ g,
                                          const float* __restrict__ b, float invM, int c,
                                          float& sc, float& sh) {
    float mu = stats[c] * invM;
    float var = stats[HH + c] * invM - mu * mu;
    float rstd = rsqrtf(var + BN_EPS);
    sc = rstd * g[c];
    sh = b[c] - mu * sc;
}

// ---------------- embed -> f16 ----------------
__global__ void embed_kernel(const float* __restrict__ xa, const float* __restrict__ xp,
                             const float* __restrict__ aw, const float* __restrict__ ab,
                             const float* __restrict__ pw, const float* __restrict__ pb,
                             unsigned short* __restrict__ h, int N) {
    int n = blockIdx.x;
    int c = threadIdx.x;
    if (n >= N) return;
    float acc = ab[c] + pb[c];
#pragma unroll
    for (int k = 0; k < 9; ++k) acc += xa[n * 9 + k] * aw[k * HH + c];
#pragma unroll
    for (int k = 0; k < 8; ++k) acc += xp[n * 8 + k] * pw[k * HH + c];
    h[(size_t)n * HH + c] = f2h(acc);
}

// ---------------- CSR build ----------------
__global__ void zero_int_kernel(int* __restrict__ p, int n) {
    int i = blockIdx.x * blockDim.x + threadIdx.x;
    if (i < n) p[i] = 0;
}

__global__ void hist_kernel(const int* __restrict__ ei, int* __restrict__ deg, int E) {
    int e = blockIdx.x * blockDim.x + threadIdx.x;
    if (e < E) atomicAdd(&deg[ei[(size_t)E + e]], 1);
}

__global__ void ps1_kernel(const int* __restrict__ deg, int* __restrict__ chunkSum, int N) {
    __shared__ int sm[CHUNK];
    int i = blockIdx.x * CHUNK + threadIdx.x;
    sm[threadIdx.x] = (i < N) ? deg[i] : 0;
    __syncthreads();
    for (int off = CHUNK / 2; off > 0; off >>= 1) {
        if (threadIdx.x < off) sm[threadIdx.x] += sm[threadIdx.x + off];
        __syncthreads();
    }
    if (threadIdx.x == 0) chunkSum[blockIdx.x] = sm[0];
}

__global__ void ps2_kernel(const int* __restrict__ chunkSum, int* __restrict__ chunkOff,
                           int nc, int* __restrict__ offs, int N, int E) {
    __shared__ int sm[CHUNK];
    int t = threadIdx.x;
    int own = (t < nc) ? chunkSum[t] : 0;
    sm[t] = own;
    for (int off = 1; off < CHUNK; off <<= 1) {
        __syncthreads();
        int v = (t >= off) ? sm[t - off] : 0;
        __syncthreads();
        sm[t] += v;
    }
    if (t < nc) chunkOff[t] = sm[t] - own;
    if (t == 0) offs[N] = E;
}

__global__ void ps3_kernel(const int* __restrict__ deg, const int* __restrict__ chunkOff,
                           int* __restrict__ offs, int* __restrict__ cursor, int N) {
    __shared__ int sm[CHUNK];
    int t = threadIdx.x;
    int i = blockIdx.x * CHUNK + t;
    int own = (i < N) ? deg[i] : 0;
    sm[t] = own;
    for (int off = 1; off < CHUNK; off <<= 1) {
        __syncthreads();
        int v = (t >= off) ? sm[t - off] : 0;
        __syncthreads();
        sm[t] += v;
    }
    if (i < N) {
        int o = chunkOff[blockIdx.x] + sm[t] - own;
        offs[i] = o;
        cursor[i] = o;
    }
}

__global__ void fill_kernel(const int* __restrict__ ei, int* __restrict__ cursor,
                            int* __restrict__ srcl, int E) {
    int e = blockIdx.x * blockDim.x + threadIdx.x;
    if (e >= E) return;
    int s = ei[e];
    int d = ei[(size_t)E + e];
    int pos = atomicAdd(&cursor[d], 1);
    srcl[pos] = s;
}

// ---------------- W transpose (both weight sets in one launch) ----------------
__global__ void transpose_w_kernel(const float* __restrict__ W1, const float* __restrict__ W2,
                                   unsigned short* __restrict__ Wt1, unsigned short* __restrict__ Wt2,
                                   int perSet) {
    __shared__ float tile[32][33];
    int id = blockIdx.x;
    const float* W = W1;
    unsigned short* Wt = Wt1;
    if (id >= perSet) { W = W2; Wt = Wt2; id -= perSet; }
    int mat = id >> 6, t = id & 63;
    int kt = (t >> 3) * 32, nt = (t & 7) * 32;
    const float* Wm = W + (size_t)mat * HH * HH;
    unsigned short* Wtm = Wt + (size_t)mat * HH * HH;
    int lx = threadIdx.x & 31, ly = threadIdx.x >> 5;
#pragma unroll
    for (int yy = 0; yy < 32; yy += 8)
        tile[ly + yy][lx] = Wm[(size_t)(kt + ly + yy) * HH + nt + lx];
    __syncthreads();
#pragma unroll
    for (int yy = 0; yy < 32; yy += 8)
        Wtm[(size_t)(nt + ly + yy) * HH + kt + lx] = f2h(tile[lx][ly + yy]);
}

// ---------------- stats init ----------------
__global__ void init_stats_kernel(float* __restrict__ stats) {
    int i = blockIdx.x * blockDim.x + threadIdx.x;
    int slot = i >> 9;
    if (slot < NSLOT) stats[(size_t)slot * 4 * HH + (i & 511)] = 0.f;
}

// ---------------- fused aggregation: z[n] = t(x[n]) + sum t(x[src_j]) ----------------
// 1 node/wave, 64 lanes x ushort4 per row, uniform j; 4 independent gathers in flight.
__global__ __launch_bounds__(256) void aggregate_fused_kernel(
        const unsigned short* __restrict__ h,
        const int* __restrict__ offs, const int* __restrict__ srcl,
        const float* __restrict__ stats, const float* __restrict__ gv,
        const float* __restrict__ bv, float invM,
        unsigned short* __restrict__ z, int N) {
    int n = blockIdx.x * 4 + (threadIdx.x >> 6);
    int l = threadIdx.x & 63;
    if (n >= N) return;
    int c = l * 4;
    const bool apply = (stats != nullptr);
    float sc0 = 1.f, sc1 = 1.f, sc2 = 1.f, sc3 = 1.f;
    float sh0 = 0.f, sh1 = 0.f, sh2 = 0.f, sh3 = 0.f;
    if (apply) {
        bn_derive(stats, gv, bv, invM, c + 0, sc0, sh0);
        bn_derive(stats, gv, bv, invM, c + 1, sc1, sh1);
        bn_derive(stats, gv, bv, invM, c + 2, sc2, sh2);
        bn_derive(stats, gv, bv, invM, c + 3, sc3, sh3);
    }

#define LOADT(row, r0, r1, r2, r3)                                      \
    {                                                                   \
        ushort4 v_ = *(const ushort4*)&h[(size_t)(row) * HH + c];       \
        r0 = h2f(v_.x); r1 = h2f(v_.y); r2 = h2f(v_.z); r3 = h2f(v_.w); \
        if (apply) {                                                    \
            r0 = fmaxf(r0 * sc0 + sh0, 0.f);                            \
            r1 = fmaxf(r1 * sc1 + sh1, 0.f);                            \
            r2 = fmaxf(r2 * sc2 + sh2, 0.f);                            \
            r3 = fmaxf(r3 * sc3 + sh3, 0.f);                            \
        }                                                               \
    }

    float a0, a1, a2, a3;
    LOADT(n, a0, a1, a2, a3);                   // self term
    int s0 = offs[n], s1 = offs[n + 1];
    int j = s0;
    for (; j + 4 <= s1; j += 4) {
        int r0 = srcl[j], r1 = srcl[j + 1], r2 = srcl[j + 2], r3 = srcl[j + 3];
        float t0, t1, t2, t3, u0, u1, u2, u3;
        float p0, p1, p2, p3, q0, q1, q2, q3;
        LOADT(r0, t0, t1, t2, t3);
        LOADT(r1, u0, u1, u2, u3);
        LOADT(r2, p0, p1, p2, p3);
        LOADT(r3, q0, q1, q2, q3);
        a0 += (t0 + u0) + (p0 + q0);
        a1 += (t1 + u1) + (p1 + q1);
        a2 += (t2 + u2) + (p2 + q2);
        a3 += (t3 + u3) + (p3 + q3);
    }
    for (; j < s1; ++j) {
        float t0, t1, t2, t3;
        LOADT(srcl[j], t0, t1, t2, t3);
        a0 += t0; a1 += t1; a2 += t2; a3 += t3;
    }
#undef LOADT
    ushort4 o;
    o.x = f2h(a0); o.y = f2h(a1); o.z = f2h(a2); o.w = f2h(a3);
    *(ushort4*)&z[(size_t)n * HH + c] = o;
}

// ---------------- f16 MFMA GEMM, templated on A-side BN fusion ----------------
// Tile 128x128, BK=64, 4 waves (2x2). Grid (2, N/128): col-fastest so the two
// blocks sharing an A-row-tile are dispatch-adjacent (A 2nd read hits L2).
// BN=false: A staged via global_load_lds (pre-transformed input).
// BN=true:  A staged global->reg->relu(x*sc+sh) in packed f16 ->ds_write (same layout);
//           sc/sh derived in prologue from bnstats (raw sums) into LDS tables.
// B always global_load_lds. Epilogue: bias + fused out-stats + LDS-staged coalesced C.
template <bool BN>
__global__ __launch_bounds__(256) void mfma_gemm_t(const unsigned short* __restrict__ A,
                                                   const unsigned short* __restrict__ Wt,
                                                   const float* __restrict__ bias,
                                                   unsigned short* __restrict__ C,
                                                   float* __restrict__ stats,
                                                   const float* __restrict__ bnstats,
                                                   const float* __restrict__ gv,
                                                   const float* __restrict__ bv,
                                                   float invM, int M) {
    __shared__ unsigned short sm[128 * 136];   // staging: [0,16384); epilogue: whole
    __shared__ _Float16 lsc[256], lsh[256];
    unsigned short* As = sm;
    unsigned short* Bs = sm + 128 * 64;
    int tid = threadIdx.x;
    int w = tid >> 6, l = tid & 63;
    int wr = w >> 1, wc = w & 1;
    int row0 = blockIdx.y * 128;
    int col0 = blockIdx.x * 128;
    int g = (l & 7) ^ (l >> 3);      // pre-swizzled source granule
    int srow = w * 8 + (l >> 3);

    if (BN) {
        float sc, sh;
        bn_derive(bnstats, gv, bv, invM, tid, sc, sh);
        lsc[tid] = (_Float16)sc;
        lsh[tid] = (_Float16)sh;
        __syncthreads();
    }

    f32x4 acc[4][4] = {};

    const unsigned short* AB = A + (size_t)row0 * HH;
    const unsigned short* WB = Wt + (size_t)col0 * HH;

    for (int k0 = 0; k0 < 256; k0 += 64) {
        f16x8 scv, shv;
        if (BN) {
            scv = *(const f16x8*)&lsc[k0 + g * 8];
            shv = *(const f16x8*)&lsh[k0 + g * 8];
        }
#pragma unroll
        for (int r = 0; r < 4; ++r) {
            int row = r * 32 + srow;
            size_t go = (size_t)row * HH + k0 + g * 8;
            int lo = (r * 32 + w * 8) * 64;
            if (BN) {
                f16x8 v = *(const f16x8*)&AB[go];
                v = v * scv + shv;
                v = __builtin_elementwise_max(v, (f16x8)(_Float16)0);
                *(f16x8*)&As[lo + l * 8] = v;
            } else {
                gload16(AB + go, &As[lo]);
            }
            gload16(WB + go, &Bs[lo]);
        }
        __syncthreads();
#pragma unroll
        for (int kh = 0; kh < 2; ++kh) {
            f16x8 af[4], bf[4];
#pragma unroll
            for (int m = 0; m < 4; ++m) {
                int rr = wr * 64 + m * 16 + (l & 15);
                int gs = (kh * 4 + (l >> 4)) ^ (rr & 7);
                af[m] = *(const f16x8*)&As[rr * 64 + gs * 8];
            }
#pragma unroll
            for (int n = 0; n < 4; ++n) {
                int rr = wc * 64 + n * 16 + (l & 15);
                int gs = (kh * 4 + (l >> 4)) ^ (rr & 7);
                bf[n] = *(const f16x8*)&Bs[rr * 64 + gs * 8];
            }
#pragma unroll
            for (int m = 0; m < 4; ++m)
#pragma unroll
                for (int n = 0; n < 4; ++n)
                    acc[m][n] = __builtin_amdgcn_mfma_f32_16x16x32_f16(af[m], bf[n], acc[m][n], 0, 0, 0);
        }
        __syncthreads();
    }

    // epilogue: bias + out-stats (register-side) + C-tile via LDS, coalesced stores
    int mvalid = M - row0;
#pragma unroll
    for (int n = 0; n < 4; ++n) {
        int colr = wc * 64 + n * 16 + (l & 15);
        float bvv = bias[col0 + colr];
        float s = 0.f, s2 = 0.f;
#pragma unroll
        for (int m = 0; m < 4; ++m) {
            int rb = wr * 64 + m * 16 + (l >> 4) * 4;
#pragma unroll
            for (int r = 0; r < 4; ++r) {
                float v = acc[m][n][r] + bvv;
                sm[(rb + r) * 136 + colr] = f2h(v);
                if (rb + r < mvalid) { s += v; s2 += v * v; }
            }
        }
        s += __shfl_xor(s, 16);   s += __shfl_xor(s, 32);
        s2 += __shfl_xor(s2, 16); s2 += __shfl_xor(s2, 32);
        if ((l >> 4) == 0) {
            atomicAdd(&stats[col0 + colr], s);
            atomicAdd(&stats[HH + col0 + colr], s2);
        }
    }
    __syncthreads();
#pragma unroll
    for (int i = 0; i < 8; ++i) {
        int ci = i * 256 + tid;          // 0..2047 chunk id
        int row = ci >> 4;
        int cq = (ci & 15) * 8;
        if (row0 + row < M) {
            uint4 v = *(const uint4*)&sm[row * 136 + cq];
            *(uint4*)&C[(size_t)(row0 + row) * HH + col0 + cq] = v;
        }
    }
}

// ---------------- BN helpers (classifier path) ----------------
__global__ void bn_stats_kernel(const float* __restrict__ X, int M, float* __restrict__ stats) {
    int c = threadIdx.x;
    int r0 = blockIdx.x * 128;
    int r1 = min(r0 + 128, M);
    float s = 0.f, s2 = 0.f;
    for (int r = r0; r < r1; ++r) {
        float v = X[(size_t)r * HH + c];
        s += v;
        s2 += v * v;
    }
    atomicAdd(&stats[c], s);
    atomicAdd(&stats[HH + c], s2);
}

__global__ void bn_finalize_kernel(float* __restrict__ stats, const float* __restrict__ g,
                                   const float* __restrict__ b, float invM) {
    int c = threadIdx.x;
    float sc, sh;
    bn_derive(stats, g, b, invM, c, sc, sh);
    stats[2 * HH + c] = sc;
    stats[3 * HH + c] = sh;
}

__global__ void bn_apply_relu_kernel(float* __restrict__ X, int n4, const float* __restrict__ stats) {
    int i = blockIdx.x * blockDim.x + threadIdx.x;
    int stride = gridDim.x * blockDim.x;
    for (; i < n4; i += stride) {
        int c4 = (i & 63) * 4;
        float4 v = ((float4*)X)[i];
        float4 sc = *(const float4*)&stats[2 * HH + c4];
        float4 sh = *(const float4*)&stats[3 * HH + c4];
        v.x = fmaxf(v.x * sc.x + sh.x, 0.f);
        v.y = fmaxf(v.y * sc.y + sh.y, 0.f);
        v.z = fmaxf(v.z * sc.z + sh.z, 0.f);
        v.w = fmaxf(v.w * sc.w + sh.w, 0.f);
        ((float4*)X)[i] = v;
    }
}

// ---------------- f32 GEMM (classifier only) ----------------
__global__ __launch_bounds__(256) void gemm_kernel(const float* __restrict__ A,
                                                   const float* __restrict__ W,
                                                   const float* __restrict__ bias,
                                                   float* __restrict__ C,
                                                   int M, int ldw) {
    __shared__ float Asm[64][33];
    __shared__ float Wsm[32][64];
    int tid = threadIdx.x;
    int tx = tid & 15, ty = tid >> 4;
    int row0 = blockIdx.x * 64;
    int col0 = blockIdx.y * 64;
    float acc[4][4] = {};

    for (int k0 = 0; k0 < 256; k0 += 32) {
#pragma unroll
        for (int t = 0; t < 2; ++t) {
            int s = tid + t * 256;
            int m = s >> 3;
            int kq = (s & 7) * 4;
            float4 v = make_float4(0.f, 0.f, 0.f, 0.f);
            if (row0 + m < M) v = *(const float4*)&A[(size_t)(row0 + m) * 256 + k0 + kq];
            Asm[m][kq + 0] = v.x; Asm[m][kq + 1] = v.y; Asm[m][kq + 2] = v.z; Asm[m][kq + 3] = v.w;
        }
#pragma unroll
        for (int t = 0; t < 2; ++t) {
            int s = tid + t * 256;
            int kk = s >> 4;
            int cq = (s & 15) * 4;
            *(float4*)&Wsm[kk][cq] = *(const float4*)&W[(size_t)(k0 + kk) * ldw + col0 + cq];
        }
        __syncthreads();
#pragma unroll
        for (int kk = 0; kk < 32; ++kk) {
            float a0 = Asm[ty * 4 + 0][kk];
            float a1 = Asm[ty * 4 + 1][kk];
            float a2 = Asm[ty * 4 + 2][kk];
            float a3 = Asm[ty * 4 + 3][kk];
            float4 wv = *(const float4*)&Wsm[kk][tx * 4];
            acc[0][0] += a0 * wv.x; acc[0][1] += a0 * wv.y; acc[0][2] += a0 * wv.z; acc[0][3] += a0 * wv.w;
            acc[1][0] += a1 * wv.x; acc[1][1] += a1 * wv.y; acc[1][2] += a1 * wv.z; acc[1][3] += a1 * wv.w;
            acc[2][0] += a2 * wv.x; acc[2][1] += a2 * wv.y; acc[2][2] += a2 * wv.z; acc[2][3] += a2 * wv.w;
            acc[3][0] += a3 * wv.x; acc[3][1] += a3 * wv.y; acc[3][2] += a3 * wv.z; acc[3][3] += a3 * wv.w;
        }
        __syncthreads();
    }

    float4 bvv = *(const float4*)&bias[col0 + tx * 4];
#pragma unroll
    for (int j = 0; j < 4; ++j) {
        int row = row0 + ty * 4 + j;
        if (row < M) {
            float4 o = make_float4(acc[j][0] + bvv.x, acc[j][1] + bvv.y,
                                   acc[j][2] + bvv.z, acc[j][3] + bvv.w);
            *(float4*)&C[(size_t)row * ldw + col0 + tx * 4] = o;
        }
    }
}

// ---------------- fused mean pool: pooled = mean relu(bn(z2_last)) ----------------
__device__ __forceinline__ int lbound(const int* a, int n, int v) {
    int lo = 0, hi = n;
    while (lo < hi) {
        int mid = (lo + hi) >> 1;
        if (a[mid] < v) lo = mid + 1; else hi = mid;
    }
    return lo;
}

__global__ void pool_fused_kernel(const unsigned short* __restrict__ Hm,
                                  const int* __restrict__ batch,
                                  const float* __restrict__ stats,
                                  const float* __restrict__ gv,
                                  const float* __restrict__ bv, float invM,
                                  int N, float* __restrict__ pooled) {
    int g = blockIdx.x;
    int c = threadIdx.x;
    int s = lbound(batch, N, g);
    int e = lbound(batch, N, g + 1);
    float sc, sh;
    bn_derive(stats, gv, bv, invM, c, sc, sh);
    float acc = 0.f;
    for (int r = s; r < e; ++r)
        acc += fmaxf(h2f(Hm[(size_t)r * HH + c]) * sc + sh, 0.f);
    pooled[(size_t)g * HH + c] = acc / (float)max(e - s, 1);
}

// ---------------- launch ----------------
extern "C" void kernel_launch(void* const* d_in, const int* in_sizes, int n_in,
                              void* d_out, int out_size, void* d_ws, size_t ws_size,
                              hipStream_t stream) {
    const float* x_atom = (const float*)d_in[0];
    const float* x_pe   = (const float*)d_in[1];
    const int* ei       = (const int*)d_in[2];
    const int* batch    = (const int*)d_in[3];
    const float* ae_w = (const float*)d_in[4];
    const float* ae_b = (const float*)d_in[5];
    const float* pe_w = (const float*)d_in[6];
    const float* pe_b = (const float*)d_in[7];
    const float* w1  = (const float*)d_in[8];
    const float* b1  = (const float*)d_in[9];
    const float* g1  = (const float*)d_in[10];
    const float* be1 = (const float*)d_in[11];
    const float* w2  = (const float*)d_in[12];
    const float* b2  = (const float*)d_in[13];
    const float* bng = (const float*)d_in[14];
    const float* bnb = (const float*)d_in[15];
    const float* cl1_w = (const float*)d_in[16];
    const float* cl1_b = (const float*)d_in[17];
    const float* clg = (const float*)d_in[18];
    const float* clb = (const float*)d_in[19];
    const float* cl2_w = (const float*)d_in[20];
    const float* cl2_b = (const float*)d_in[21];

    const int N = in_sizes[3];
    const int E = in_sizes[2] / 2;
    const int T = in_sizes[21];
    const int B = out_size / T;
    const int Lnum = in_sizes[9] / HH;
    const int nc = cdiv(N, CHUNK);
    const int Npad = cdiv(N, 128) * 128;
    const size_t P = (size_t)Npad * HH;

    unsigned short* X = (unsigned short*)d_ws;
    unsigned short* Y = X + P;
    unsigned short* wt1 = Y + P;                        // L*HH*HH f16
    unsigned short* wt2 = wt1 + (size_t)Lnum * HH * HH;
    float* stats = (float*)(wt2 + (size_t)Lnum * HH * HH);   // NSLOT x 4*HH
    float* pooled = stats + (size_t)NSLOT * 4 * HH;
    float* zc = pooled + (size_t)B * HH;
    int* deg = (int*)(zc + (size_t)B * HH);
    int* offs = deg + N;
    int* cursor = offs + N + 1;
    int* chunkSum = cursor + N;
    int* chunkOff = chunkSum + 256;
    int* srcl = chunkOff + 256;

    const int BH4 = B * (HH / 4);
    const float invN = 1.f / (float)N;

    // ---- CSR build ----
    zero_int_kernel<<<cdiv(N, 256), 256, 0, stream>>>(deg, N);
    hist_kernel<<<cdiv(E, 256), 256, 0, stream>>>(ei, deg, E);
    ps1_kernel<<<nc, CHUNK, 0, stream>>>(deg, chunkSum, N);
    ps2_kernel<<<1, CHUNK, 0, stream>>>(chunkSum, chunkOff, nc, offs, N, E);
    ps3_kernel<<<nc, CHUNK, 0, stream>>>(deg, chunkOff, offs, cursor, N);
    fill_kernel<<<cdiv(E, 256), 256, 0, stream>>>(ei, cursor, srcl, E);

    // ---- weight transpose (both sets, one launch) ----
    transpose_w_kernel<<<2 * Lnum * 64, 256, 0, stream>>>(w1, w2, wt1, wt2, Lnum * 64);

    // ---- stats init (all slots, once) ----
    init_stats_kernel<<<cdiv(NSLOT * 512, 256), 256, 0, stream>>>(stats);

    // ---- embed ----
    embed_kernel<<<N, HH, 0, stream>>>(x_atom, x_pe, ae_w, ae_b, pe_w, pe_b, X, N);

    dim3 mf_grid(2, cdiv(N, 128));   // col-fastest: A-tile pair dispatch-adjacent

    unsigned short *in = X, *ot = Y;

    for (int i = 0; i < Lnum; ++i) {
        float* slot1 = stats + (size_t)(2 * i) * 4 * HH;
        float* slot2 = stats + (size_t)(2 * i + 1) * 4 * HH;
        const float* aggStats = (i == 0) ? nullptr : stats + (size_t)(2 * i - 1) * 4 * HH;
        const float* aggG = (i == 0) ? nullptr : bng + (size_t)(i - 1) * HH;
        const float* aggB = (i == 0) ? nullptr : bnb + (size_t)(i - 1) * HH;

        // z = t(in) + gather-sum t(in[src]) : in -> ot
        aggregate_fused_kernel<<<cdiv(N, 4), 256, 0, stream>>>(in, offs, srcl,
                                                               aggStats, aggG, aggB, invN, ot, N);

        // z1 = z @ w1 + b1 : ot -> in (raw z1; inner BN fused into GEMM2's A-staging)
        mfma_gemm_t<false><<<mf_grid, 256, 0, stream>>>(ot, wt1 + (size_t)i * HH * HH,
                                                        b1 + (size_t)i * HH, in, slot1,
                                                        nullptr, nullptr, nullptr, 0.f, N);

        // z2 = relu(bn(z1)) @ w2 + b2 : in -> ot (BN applied during A staging)
        mfma_gemm_t<true><<<mf_grid, 256, 0, stream>>>(in, wt2 + (size_t)i * HH * HH,
                                                       b2 + (size_t)i * HH, ot, slot2,
                                                       slot1, g1 + (size_t)i * HH,
                                                       be1 + (size_t)i * HH, invN, N);

        unsigned short* t = in; in = ot; ot = t;
    }

    // ---- fused mean pool (applies last outer BN+relu) ----
    pool_fused_kernel<<<B, HH, 0, stream>>>(in, batch,
                                            stats + (size_t)(2 * Lnum - 1) * 4 * HH,
                                            bng + (size_t)(Lnum - 1) * HH,
                                            bnb + (size_t)(Lnum - 1) * HH, invN, N, pooled);

    // ---- classifier (f32 path, slot 10) ----
    float* slotC = stats + (size_t)10 * 4 * HH;
    dim3 cls_grid1(cdiv(B, 64), HH / 64);
    gemm_kernel<<<cls_grid1, 256, 0, stream>>>(pooled, cl1_w, cl1_b, zc, B, HH);
    bn_stats_kernel<<<cdiv(B, 128), HH, 0, stream>>>(zc, B, slotC);
    bn_finalize_kernel<<<1, HH, 0, stream>>>(slotC, clg, clb, 1.f / B);
    bn_apply_relu_kernel<<<min(2048, cdiv(BH4, 256)), 256, 0, stream>>>(zc, BH4, slotC);

    dim3 cls_grid2(cdiv(B, 64), T / 64);
    gemm_kernel<<<cls_grid2, 256, 0, stream>>>(zc, cl2_w, cl2_b, (float*)d_out, B, T);
}

// Round 11
// 1017.665 us; speedup vs baseline: 1.5390x; 1.0281x over previous
//
#include <hip/hip_runtime.h>
#include <hip/hip_bf16.h>
#include <stdint.h>

#define HH 256
#define BN_EPS 1e-5f
#define CHUNK 256
#define NSLOT 12   // stats slots: layer i -> 2i (inner), 2i+1 (outer); classifier -> 10

static inline int cdiv(int a, int b) { return (a + b - 1) / b; }

typedef _Float16 f16x8 __attribute__((ext_vector_type(8)));
typedef __attribute__((ext_vector_type(4))) float f32x4;

__device__ __forceinline__ unsigned short f2h(float f) {
    _Float16 h = (_Float16)f;            // v_cvt_f16_f32, RNE
    unsigned short u;
    __builtin_memcpy(&u, &h, 2);
    return u;
}
__device__ __forceinline__ float h2f(unsigned short u) {
    _Float16 h;
    __builtin_memcpy(&h, &u, 2);
    return (float)h;
}

__device__ __forceinline__ void gload16(const void* g, void* lds) {
    __builtin_amdgcn_global_load_lds((const __attribute__((address_space(1))) unsigned int*)g,
                                     (__attribute__((address_space(3))) unsigned int*)lds, 16, 0, 0);
}

// derive BN scale/shift for one channel from raw sums
__device__ __forceinline__ void bn_derive(const float* __restrict__ stats, const float* __restrict__ g,
                                          const float* __restrict__ b, float invM, int c,
                                          float& sc, float& sh) {
    float mu = stats[c] * invM;
    float var = stats[HH + c] * invM - mu * mu;
    float rstd = rsqrtf(var + BN_EPS);
    sc = rstd * g[c];
    sh = b[c] - mu * sc;
}

// ---------------- embed -> f16 ----------------
__global__ void embed_kernel(const float* __restrict__ xa, const float* __restrict__ xp,
                             const float* __restrict__ aw, const float* __restrict__ ab,
                             const float* __restrict__ pw, const float* __restrict__ pb,
                             unsigned short* __restrict__ h, int N) {
    int n = blockIdx.x;
    int c = threadIdx.x;
    if (n >= N) return;
    float acc = ab[c] + pb[c];
#pragma unroll
    for (int k = 0; k < 9; ++k) acc += xa[n * 9 + k] * aw[k * HH + c];
#pragma unroll
    for (int k = 0; k < 8; ++k) acc += xp[n * 8 + k] * pw[k * HH + c];
    h[(size_t)n * HH + c] = f2h(acc);
}

// ---------------- CSR build ----------------
__global__ void zero_int_kernel(int* __restrict__ p, int n) {
    int i = blockIdx.x * blockDim.x + threadIdx.x;
    if (i < n) p[i] = 0;
}

__global__ void hist_kernel(const int* __restrict__ ei, int* __restrict__ deg, int E) {
    int e = blockIdx.x * blockDim.x + threadIdx.x;
    if (e < E) atomicAdd(&deg[ei[(size_t)E + e]], 1);
}

__global__ void ps1_kernel(const int* __restrict__ deg, int* __restrict__ chunkSum, int N) {
    __shared__ int sm[CHUNK];
    int i = blockIdx.x * CHUNK + threadIdx.x;
    sm[threadIdx.x] = (i < N) ? deg[i] : 0;
    __syncthreads();
    for (int off = CHUNK / 2; off > 0; off >>= 1) {
        if (threadIdx.x < off) sm[threadIdx.x] += sm[threadIdx.x + off];
        __syncthreads();
    }
    if (threadIdx.x == 0) chunkSum[blockIdx.x] = sm[0];
}

__global__ void ps2_kernel(const int* __restrict__ chunkSum, int* __restrict__ chunkOff,
                           int nc, int* __restrict__ offs, int N, int E) {
    __shared__ int sm[CHUNK];
    int t = threadIdx.x;
    int own = (t < nc) ? chunkSum[t] : 0;
    sm[t] = own;
    for (int off = 1; off < CHUNK; off <<= 1) {
        __syncthreads();
        int v = (t >= off) ? sm[t - off] : 0;
        __syncthreads();
        sm[t] += v;
    }
    if (t < nc) chunkOff[t] = sm[t] - own;
    if (t == 0) offs[N] = E;
}

__global__ void ps3_kernel(const int* __restrict__ deg, const int* __restrict__ chunkOff,
                           int* __restrict__ offs, int* __restrict__ cursor, int N) {
    __shared__ int sm[CHUNK];
    int t = threadIdx.x;
    int i = blockIdx.x * CHUNK + t;
    int own = (i < N) ? deg[i] : 0;
    sm[t] = own;
    for (int off = 1; off < CHUNK; off <<= 1) {
        __syncthreads();
        int v = (t >= off) ? sm[t - off] : 0;
        __syncthreads();
        sm[t] += v;
    }
    if (i < N) {
        int o = chunkOff[blockIdx.x] + sm[t] - own;
        offs[i] = o;
        cursor[i] = o;
    }
}

__global__ void fill_kernel(const int* __restrict__ ei, int* __restrict__ cursor,
                            int* __restrict__ srcl, int E) {
    int e = blockIdx.x * blockDim.x + threadIdx.x;
    if (e >= E) return;
    int s = ei[e];
    int d = ei[(size_t)E + e];
    int pos = atomicAdd(&cursor[d], 1);
    srcl[pos] = s;
}

// ---------------- W transpose (both weight sets in one launch) ----------------
__global__ void transpose_w_kernel(const float* __restrict__ W1, const float* __restrict__ W2,
                                   unsigned short* __restrict__ Wt1, unsigned short* __restrict__ Wt2,
                                   int perSet) {
    __shared__ float tile[32][33];
    int id = blockIdx.x;
    const float* W = W1;
    unsigned short* Wt = Wt1;
    if (id >= perSet) { W = W2; Wt = Wt2; id -= perSet; }
    int mat = id >> 6, t = id & 63;
    int kt = (t >> 3) * 32, nt = (t & 7) * 32;
    const float* Wm = W + (size_t)mat * HH * HH;
    unsigned short* Wtm = Wt + (size_t)mat * HH * HH;
    int lx = threadIdx.x & 31, ly = threadIdx.x >> 5;
#pragma unroll
    for (int yy = 0; yy < 32; yy += 8)
        tile[ly + yy][lx] = Wm[(size_t)(kt + ly + yy) * HH + nt + lx];
    __syncthreads();
#pragma unroll
    for (int yy = 0; yy < 32; yy += 8)
        Wtm[(size_t)(nt + ly + yy) * HH + kt + lx] = f2h(tile[lx][ly + yy]);
}

// ---------------- stats init ----------------
__global__ void init_stats_kernel(float* __restrict__ stats) {
    int i = blockIdx.x * blockDim.x + threadIdx.x;
    int slot = i >> 9;
    if (slot < NSLOT) stats[(size_t)slot * 4 * HH + (i & 511)] = 0.f;
}

// ---------------- fused aggregation: z[n] = t(x[n]) + sum t(x[src_j]) ----------------
// 1 node/wave, 64 lanes x ushort4 per row, uniform j; 4 independent gathers in flight.
__global__ __launch_bounds__(256) void aggregate_fused_kernel(
        const unsigned short* __restrict__ h,
        const int* __restrict__ offs, const int* __restrict__ srcl,
        const float* __restrict__ stats, const float* __restrict__ gv,
        const float* __restrict__ bv, float invM,
        unsigned short* __restrict__ z, int N) {
    int n = blockIdx.x * 4 + (threadIdx.x >> 6);
    int l = threadIdx.x & 63;
    if (n >= N) return;
    int c = l * 4;
    const bool apply = (stats != nullptr);
    float sc0 = 1.f, sc1 = 1.f, sc2 = 1.f, sc3 = 1.f;
    float sh0 = 0.f, sh1 = 0.f, sh2 = 0.f, sh3 = 0.f;
    if (apply) {
        bn_derive(stats, gv, bv, invM, c + 0, sc0, sh0);
        bn_derive(stats, gv, bv, invM, c + 1, sc1, sh1);
        bn_derive(stats, gv, bv, invM, c + 2, sc2, sh2);
        bn_derive(stats, gv, bv, invM, c + 3, sc3, sh3);
    }

#define LOADT(row, r0, r1, r2, r3)                                      \
    {                                                                   \
        ushort4 v_ = *(const ushort4*)&h[(size_t)(row) * HH + c];       \
        r0 = h2f(v_.x); r1 = h2f(v_.y); r2 = h2f(v_.z); r3 = h2f(v_.w); \
        if (apply) {                                                    \
            r0 = fmaxf(r0 * sc0 + sh0, 0.f);                            \
            r1 = fmaxf(r1 * sc1 + sh1, 0.f);                            \
            r2 = fmaxf(r2 * sc2 + sh2, 0.f);                            \
            r3 = fmaxf(r3 * sc3 + sh3, 0.f);                            \
        }                                                               \
    }

    float a0, a1, a2, a3;
    LOADT(n, a0, a1, a2, a3);                   // self term
    int s0 = offs[n], s1 = offs[n + 1];
    int j = s0;
    for (; j + 4 <= s1; j += 4) {
        int r0 = srcl[j], r1 = srcl[j + 1], r2 = srcl[j + 2], r3 = srcl[j + 3];
        float t0, t1, t2, t3, u0, u1, u2, u3;
        float p0, p1, p2, p3, q0, q1, q2, q3;
        LOADT(r0, t0, t1, t2, t3);
        LOADT(r1, u0, u1, u2, u3);
        LOADT(r2, p0, p1, p2, p3);
        LOADT(r3, q0, q1, q2, q3);
        a0 += (t0 + u0) + (p0 + q0);
        a1 += (t1 + u1) + (p1 + q1);
        a2 += (t2 + u2) + (p2 + q2);
        a3 += (t3 + u3) + (p3 + q3);
    }
    for (; j < s1; ++j) {
        float t0, t1, t2, t3;
        LOADT(srcl[j], t0, t1, t2, t3);
        a0 += t0; a1 += t1; a2 += t2; a3 += t3;
    }
#undef LOADT
    ushort4 o;
    o.x = f2h(a0); o.y = f2h(a1); o.z = f2h(a2); o.w = f2h(a3);
    *(ushort4*)&z[(size_t)n * HH + c] = o;
}

// ---------------- f16 MFMA GEMM, templated on A-side BN fusion ----------------
// Tile 128x128, BK=64, 4 waves (2x2). Grid (2, N/128): col-fastest so the two
// blocks sharing an A-row-tile are dispatch-adjacent (A 2nd read hits L2).
// A and B both staged via global_load_lds (async). BN=true applies
// relu(x*sc+sh) to the A FRAGMENTS after ds_read: the fragment's k-slice
// (= BN channel) is m-independent: k = k0 + (kh*4 + (l>>4))*8 + [0,8),
// so one f16x8 sc/sh LDS read per kh serves all 4 af[m]. ~64 VALU per
// K-step vs 640 MFMA cycles -> hidden; async staging path preserved.
template <bool BN>
__global__ __launch_bounds__(256) void mfma_gemm_t(const unsigned short* __restrict__ A,
                                                   const unsigned short* __restrict__ Wt,
                                                   const float* __restrict__ bias,
                                                   unsigned short* __restrict__ C,
                                                   float* __restrict__ stats,
                                                   const float* __restrict__ bnstats,
                                                   const float* __restrict__ gv,
                                                   const float* __restrict__ bv,
                                                   float invM, int M) {
    __shared__ unsigned short sm[128 * 136];   // staging: [0,16384); epilogue: whole
    __shared__ __align__(16) _Float16 lsc[256];
    __shared__ __align__(16) _Float16 lsh[256];
    unsigned short* As = sm;
    unsigned short* Bs = sm + 128 * 64;
    int tid = threadIdx.x;
    int w = tid >> 6, l = tid & 63;
    int wr = w >> 1, wc = w & 1;
    int row0 = blockIdx.y * 128;
    int col0 = blockIdx.x * 128;
    int g = (l & 7) ^ (l >> 3);      // pre-swizzled source granule
    int srow = w * 8 + (l >> 3);

    if (BN) {
        float sc, sh;
        bn_derive(bnstats, gv, bv, invM, tid, sc, sh);
        lsc[tid] = (_Float16)sc;
        lsh[tid] = (_Float16)sh;
        __syncthreads();
    }

    f32x4 acc[4][4] = {};

    const unsigned short* AB = A + (size_t)row0 * HH;
    const unsigned short* WB = Wt + (size_t)col0 * HH;

    for (int k0 = 0; k0 < 256; k0 += 64) {
#pragma unroll
        for (int r = 0; r < 4; ++r) {
            int row = r * 32 + srow;
            size_t go = (size_t)row * HH + k0 + g * 8;
            int lo = (r * 32 + w * 8) * 64;
            gload16(AB + go, &As[lo]);
            gload16(WB + go, &Bs[lo]);
        }
        __syncthreads();
#pragma unroll
        for (int kh = 0; kh < 2; ++kh) {
            f16x8 af[4], bf[4];
            f16x8 scv, shv;
            if (BN) {
                int kb = k0 + (kh * 4 + (l >> 4)) * 8;
                scv = *(const f16x8*)&lsc[kb];
                shv = *(const f16x8*)&lsh[kb];
            }
#pragma unroll
            for (int m = 0; m < 4; ++m) {
                int rr = wr * 64 + m * 16 + (l & 15);
                int gs = (kh * 4 + (l >> 4)) ^ (rr & 7);
                af[m] = *(const f16x8*)&As[rr * 64 + gs * 8];
                if (BN) {
                    af[m] = af[m] * scv + shv;
                    af[m] = __builtin_elementwise_max(af[m], (f16x8)(_Float16)0);
                }
            }
#pragma unroll
            for (int n = 0; n < 4; ++n) {
                int rr = wc * 64 + n * 16 + (l & 15);
                int gs = (kh * 4 + (l >> 4)) ^ (rr & 7);
                bf[n] = *(const f16x8*)&Bs[rr * 64 + gs * 8];
            }
#pragma unroll
            for (int m = 0; m < 4; ++m)
#pragma unroll
                for (int n = 0; n < 4; ++n)
                    acc[m][n] = __builtin_amdgcn_mfma_f32_16x16x32_f16(af[m], bf[n], acc[m][n], 0, 0, 0);
        }
        __syncthreads();
    }

    // epilogue: bias + out-stats (register-side) + C-tile via LDS, coalesced stores
    int mvalid = M - row0;
#pragma unroll
    for (int n = 0; n < 4; ++n) {
        int colr = wc * 64 + n * 16 + (l & 15);
        float bvv = bias[col0 + colr];
        float s = 0.f, s2 = 0.f;
#pragma unroll
        for (int m = 0; m < 4; ++m) {
            int rb = wr * 64 + m * 16 + (l >> 4) * 4;
#pragma unroll
            for (int r = 0; r < 4; ++r) {
                float v = acc[m][n][r] + bvv;
                sm[(rb + r) * 136 + colr] = f2h(v);
                if (rb + r < mvalid) { s += v; s2 += v * v; }
            }
        }
        s += __shfl_xor(s, 16);   s += __shfl_xor(s, 32);
        s2 += __shfl_xor(s2, 16); s2 += __shfl_xor(s2, 32);
        if ((l >> 4) == 0) {
            atomicAdd(&stats[col0 + colr], s);
            atomicAdd(&stats[HH + col0 + colr], s2);
        }
    }
    __syncthreads();
#pragma unroll
    for (int i = 0; i < 8; ++i) {
        int ci = i * 256 + tid;          // 0..2047 chunk id
        int row = ci >> 4;
        int cq = (ci & 15) * 8;
        if (row0 + row < M) {
            uint4 v = *(const uint4*)&sm[row * 136 + cq];
            *(uint4*)&C[(size_t)(row0 + row) * HH + col0 + cq] = v;
        }
    }
}

// ---------------- BN helpers (classifier path) ----------------
__global__ void bn_stats_kernel(const float* __restrict__ X, int M, float* __restrict__ stats) {
    int c = threadIdx.x;
    int r0 = blockIdx.x * 128;
    int r1 = min(r0 + 128, M);
    float s = 0.f, s2 = 0.f;
    for (int r = r0; r < r1; ++r) {
        float v = X[(size_t)r * HH + c];
        s += v;
        s2 += v * v;
    }
    atomicAdd(&stats[c], s);
    atomicAdd(&stats[HH + c], s2);
}

__global__ void bn_finalize_kernel(float* __restrict__ stats, const float* __restrict__ g,
                                   const float* __restrict__ b, float invM) {
    int c = threadIdx.x;
    float sc, sh;
    bn_derive(stats, g, b, invM, c, sc, sh);
    stats[2 * HH + c] = sc;
    stats[3 * HH + c] = sh;
}

__global__ void bn_apply_relu_kernel(float* __restrict__ X, int n4, const float* __restrict__ stats) {
    int i = blockIdx.x * blockDim.x + threadIdx.x;
    int stride = gridDim.x * blockDim.x;
    for (; i < n4; i += stride) {
        int c4 = (i & 63) * 4;
        float4 v = ((float4*)X)[i];
        float4 sc = *(const float4*)&stats[2 * HH + c4];
        float4 sh = *(const float4*)&stats[3 * HH + c4];
        v.x = fmaxf(v.x * sc.x + sh.x, 0.f);
        v.y = fmaxf(v.y * sc.y + sh.y, 0.f);
        v.z = fmaxf(v.z * sc.z + sh.z, 0.f);
        v.w = fmaxf(v.w * sc.w + sh.w, 0.f);
        ((float4*)X)[i] = v;
    }
}

// ---------------- f32 GEMM (classifier only) ----------------
__global__ __launch_bounds__(256) void gemm_kernel(const float* __restrict__ A,
                                                   const float* __restrict__ W,
                                                   const float* __restrict__ bias,
                                                   float* __restrict__ C,
                                                   int M, int ldw) {
    __shared__ float Asm[64][33];
    __shared__ float Wsm[32][64];
    int tid = threadIdx.x;
    int tx = tid & 15, ty = tid >> 4;
    int row0 = blockIdx.x * 64;
    int col0 = blockIdx.y * 64;
    float acc[4][4] = {};

    for (int k0 = 0; k0 < 256; k0 += 32) {
#pragma unroll
        for (int t = 0; t < 2; ++t) {
            int s = tid + t * 256;
            int m = s >> 3;
            int kq = (s & 7) * 4;
            float4 v = make_float4(0.f, 0.f, 0.f, 0.f);
            if (row0 + m < M) v = *(const float4*)&A[(size_t)(row0 + m) * 256 + k0 + kq];
            Asm[m][kq + 0] = v.x; Asm[m][kq + 1] = v.y; Asm[m][kq + 2] = v.z; Asm[m][kq + 3] = v.w;
        }
#pragma unroll
        for (int t = 0; t < 2; ++t) {
            int s = tid + t * 256;
            int kk = s >> 4;
            int cq = (s & 15) * 4;
            *(float4*)&Wsm[kk][cq] = *(const float4*)&W[(size_t)(k0 + kk) * ldw + col0 + cq];
        }
        __syncthreads();
#pragma unroll
        for (int kk = 0; kk < 32; ++kk) {
            float a0 = Asm[ty * 4 + 0][kk];
            float a1 = Asm[ty * 4 + 1][kk];
            float a2 = Asm[ty * 4 + 2][kk];
            float a3 = Asm[ty * 4 + 3][kk];
            float4 wv = *(const float4*)&Wsm[kk][tx * 4];
            acc[0][0] += a0 * wv.x; acc[0][1] += a0 * wv.y; acc[0][2] += a0 * wv.z; acc[0][3] += a0 * wv.w;
            acc[1][0] += a1 * wv.x; acc[1][1] += a1 * wv.y; acc[1][2] += a1 * wv.z; acc[1][3] += a1 * wv.w;
            acc[2][0] += a2 * wv.x; acc[2][1] += a2 * wv.y; acc[2][2] += a2 * wv.z; acc[2][3] += a2 * wv.w;
            acc[3][0] += a3 * wv.x; acc[3][1] += a3 * wv.y; acc[3][2] += a3 * wv.z; acc[3][3] += a3 * wv.w;
        }
        __syncthreads();
    }

    float4 bvv = *(const float4*)&bias[col0 + tx * 4];
#pragma unroll
    for (int j = 0; j < 4; ++j) {
        int row = row0 + ty * 4 + j;
        if (row < M) {
            float4 o = make_float4(acc[j][0] + bvv.x, acc[j][1] + bvv.y,
                                   acc[j][2] + bvv.z, acc[j][3] + bvv.w);
            *(float4*)&C[(size_t)row * ldw + col0 + tx * 4] = o;
        }
    }
}

// ---------------- fused mean pool: pooled = mean relu(bn(z2_last)) ----------------
__device__ __forceinline__ int lbound(const int* a, int n, int v) {
    int lo = 0, hi = n;
    while (lo < hi) {
        int mid = (lo + hi) >> 1;
        if (a[mid] < v) lo = mid + 1; else hi = mid;
    }
    return lo;
}

__global__ void pool_fused_kernel(const unsigned short* __restrict__ Hm,
                                  const int* __restrict__ batch,
                                  const float* __restrict__ stats,
                                  const float* __restrict__ gv,
                                  const float* __restrict__ bv, float invM,
                                  int N, float* __restrict__ pooled) {
    int g = blockIdx.x;
    int c = threadIdx.x;
    int s = lbound(batch, N, g);
    int e = lbound(batch, N, g + 1);
    float sc, sh;
    bn_derive(stats, gv, bv, invM, c, sc, sh);
    float acc = 0.f;
    for (int r = s; r < e; ++r)
        acc += fmaxf(h2f(Hm[(size_t)r * HH + c]) * sc + sh, 0.f);
    pooled[(size_t)g * HH + c] = acc / (float)max(e - s, 1);
}

// ---------------- launch ----------------
extern "C" void kernel_launch(void* const* d_in, const int* in_sizes, int n_in,
                              void* d_out, int out_size, void* d_ws, size_t ws_size,
                              hipStream_t stream) {
    const float* x_atom = (const float*)d_in[0];
    const float* x_pe   = (const float*)d_in[1];
    const int* ei       = (const int*)d_in[2];
    const int* batch    = (const int*)d_in[3];
    const float* ae_w = (const float*)d_in[4];
    const float* ae_b = (const float*)d_in[5];
    const float* pe_w = (const float*)d_in[6];
    const float* pe_b = (const float*)d_in[7];
    const float* w1  = (const float*)d_in[8];
    const float* b1  = (const float*)d_in[9];
    const float* g1  = (const float*)d_in[10];
    const float* be1 = (const float*)d_in[11];
    const float* w2  = (const float*)d_in[12];
    const float* b2  = (const float*)d_in[13];
    const float* bng = (const float*)d_in[14];
    const float* bnb = (const float*)d_in[15];
    const float* cl1_w = (const float*)d_in[16];
    const float* cl1_b = (const float*)d_in[17];
    const float* clg = (const float*)d_in[18];
    const float* clb = (const float*)d_in[19];
    const float* cl2_w = (const float*)d_in[20];
    const float* cl2_b = (const float*)d_in[21];

    const int N = in_sizes[3];
    const int E = in_sizes[2] / 2;
    const int T = in_sizes[21];
    const int B = out_size / T;
    const int Lnum = in_sizes[9] / HH;
    const int nc = cdiv(N, CHUNK);
    const int Npad = cdiv(N, 128) * 128;
    const size_t P = (size_t)Npad * HH;

    unsigned short* X = (unsigned short*)d_ws;
    unsigned short* Y = X + P;
    unsigned short* wt1 = Y + P;                        // L*HH*HH f16
    unsigned short* wt2 = wt1 + (size_t)Lnum * HH * HH;
    float* stats = (float*)(wt2 + (size_t)Lnum * HH * HH);   // NSLOT x 4*HH
    float* pooled = stats + (size_t)NSLOT * 4 * HH;
    float* zc = pooled + (size_t)B * HH;
    int* deg = (int*)(zc + (size_t)B * HH);
    int* offs = deg + N;
    int* cursor = offs + N + 1;
    int* chunkSum = cursor + N;
    int* chunkOff = chunkSum + 256;
    int* srcl = chunkOff + 256;

    const int BH4 = B * (HH / 4);
    const float invN = 1.f / (float)N;

    // ---- CSR build ----
    zero_int_kernel<<<cdiv(N, 256), 256, 0, stream>>>(deg, N);
    hist_kernel<<<cdiv(E, 256), 256, 0, stream>>>(ei, deg, E);
    ps1_kernel<<<nc, CHUNK, 0, stream>>>(deg, chunkSum, N);
    ps2_kernel<<<1, CHUNK, 0, stream>>>(chunkSum, chunkOff, nc, offs, N, E);
    ps3_kernel<<<nc, CHUNK, 0, stream>>>(deg, chunkOff, offs, cursor, N);
    fill_kernel<<<cdiv(E, 256), 256, 0, stream>>>(ei, cursor, srcl, E);

    // ---- weight transpose (both sets, one launch) ----
    transpose_w_kernel<<<2 * Lnum * 64, 256, 0, stream>>>(w1, w2, wt1, wt2, Lnum * 64);

    // ---- stats init (all slots, once) ----
    init_stats_kernel<<<cdiv(NSLOT * 512, 256), 256, 0, stream>>>(stats);

    // ---- embed ----
    embed_kernel<<<N, HH, 0, stream>>>(x_atom, x_pe, ae_w, ae_b, pe_w, pe_b, X, N);

    dim3 mf_grid(2, cdiv(N, 128));   // col-fastest: A-tile pair dispatch-adjacent

    unsigned short *in = X, *ot = Y;

    for (int i = 0; i < Lnum; ++i) {
        float* slot1 = stats + (size_t)(2 * i) * 4 * HH;
        float* slot2 = stats + (size_t)(2 * i + 1) * 4 * HH;
        const float* aggStats = (i == 0) ? nullptr : stats + (size_t)(2 * i - 1) * 4 * HH;
        const float* aggG = (i == 0) ? nullptr : bng + (size_t)(i - 1) * HH;
        const float* aggB = (i == 0) ? nullptr : bnb + (size_t)(i - 1) * HH;

        // z = t(in) + gather-sum t(in[src]) : in -> ot
        aggregate_fused_kernel<<<cdiv(N, 4), 256, 0, stream>>>(in, offs, srcl,
                                                               aggStats, aggG, aggB, invN, ot, N);

        // z1 = z @ w1 + b1 : ot -> in (raw z1; inner BN applied in GEMM2 fragments)
        mfma_gemm_t<false><<<mf_grid, 256, 0, stream>>>(ot, wt1 + (size_t)i * HH * HH,
                                                        b1 + (size_t)i * HH, in, slot1,
                                                        nullptr, nullptr, nullptr, 0.f, N);

        // z2 = relu(bn(z1)) @ w2 + b2 : in -> ot (BN on A fragments, async staging kept)
        mfma_gemm_t<true><<<mf_grid, 256, 0, stream>>>(in, wt2 + (size_t)i * HH * HH,
                                                       b2 + (size_t)i * HH, ot, slot2,
                                                       slot1, g1 + (size_t)i * HH,
                                                       be1 + (size_t)i * HH, invN, N);

        unsigned short* t = in; in = ot; ot = t;
    }

    // ---- fused mean pool (applies last outer BN+relu) ----
    pool_fused_kernel<<<B, HH, 0, stream>>>(in, batch,
                                            stats + (size_t)(2 * Lnum - 1) * 4 * HH,
                                            bng + (size_t)(Lnum - 1) * HH,
                                            bnb + (size_t)(Lnum - 1) * HH, invN, N, pooled);

    // ---- classifier (f32 path, slot 10) ----
    float* slotC = stats + (size_t)10 * 4 * HH;
    dim3 cls_grid1(cdiv(B, 64), HH / 64);
    gemm_kernel<<<cls_grid1, 256, 0, stream>>>(pooled, cl1_w, cl1_b, zc, B, HH);
    bn_stats_kernel<<<cdiv(B, 128), HH, 0, stream>>>(zc, B, slotC);
    bn_finalize_kernel<<<1, HH, 0, stream>>>(slotC, clg, clb, 1.f / B);
    bn_apply_relu_kernel<<<min(2048, cdiv(BH4, 256)), 256, 0, stream>>>(zc, BH4, slotC);

    dim3 cls_grid2(cdiv(B, 64), T / 64);
    gemm_kernel<<<cls_grid2, 256, 0, stream>>>(zc, cl2_w, cl2_b, (float*)d_out, B, T);
}

// Round 12
// 888.553 us; speedup vs baseline: 1.7626x; 1.1453x over previous
//
#include <hip/hip_runtime.h>
#include <hip/hip_bf16.h>
#include <stdint.h>

#define HH 256
#define BN_EPS 1e-5f
#define CHUNK 256
#define NSLOT 12   // stats slots: layer i -> 2i (inner), 2i+1 (outer); classifier -> 10

static inline int cdiv(int a, int b) { return (a + b - 1) / b; }

typedef _Float16 f16x8 __attribute__((ext_vector_type(8)));
typedef __attribute__((ext_vector_type(4))) float f32x4;

__device__ __forceinline__ unsigned short f2h(float f) {
    _Float16 h = (_Float16)f;            // v_cvt_f16_f32, RNE
    unsigned short u;
    __builtin_memcpy(&u, &h, 2);
    return u;
}
__device__ __forceinline__ float h2f(unsigned short u) {
    _Float16 h;
    __builtin_memcpy(&h, &u, 2);
    return (float)h;
}

__device__ __forceinline__ void gload16(const void* g, void* lds) {
    __builtin_amdgcn_global_load_lds((const __attribute__((address_space(1))) unsigned int*)g,
                                     (__attribute__((address_space(3))) unsigned int*)lds, 16, 0, 0);
}

// derive BN scale/shift for one channel from raw sums
__device__ __forceinline__ void bn_derive(const float* __restrict__ stats, const float* __restrict__ g,
                                          const float* __restrict__ b, float invM, int c,
                                          float& sc, float& sh) {
    float mu = stats[c] * invM;
    float var = stats[HH + c] * invM - mu * mu;
    float rstd = rsqrtf(var + BN_EPS);
    sc = rstd * g[c];
    sh = b[c] - mu * sc;
}

// ---------------- embed -> f16 ----------------
__global__ void embed_kernel(const float* __restrict__ xa, const float* __restrict__ xp,
                             const float* __restrict__ aw, const float* __restrict__ ab,
                             const float* __restrict__ pw, const float* __restrict__ pb,
                             unsigned short* __restrict__ h, int N) {
    int n = blockIdx.x;
    int c = threadIdx.x;
    if (n >= N) return;
    float acc = ab[c] + pb[c];
#pragma unroll
    for (int k = 0; k < 9; ++k) acc += xa[n * 9 + k] * aw[k * HH + c];
#pragma unroll
    for (int k = 0; k < 8; ++k) acc += xp[n * 8 + k] * pw[k * HH + c];
    h[(size_t)n * HH + c] = f2h(acc);
}

// ---------------- setup: zero deg[N] + zero stats sums (one launch) ----------------
__global__ void setup_kernel(int* __restrict__ deg, int N, float* __restrict__ stats) {
    int i = blockIdx.x * blockDim.x + threadIdx.x;
    if (i < N) deg[i] = 0;
    if (i < NSLOT * 512) {
        int slot = i >> 9;
        stats[(size_t)slot * 4 * HH + (i & 511)] = 0.f;
    }
}

// ---------------- CSR build ----------------
__global__ void hist_kernel(const int* __restrict__ ei, int* __restrict__ deg, int E) {
    int e = blockIdx.x * blockDim.x + threadIdx.x;
    if (e < E) atomicAdd(&deg[ei[(size_t)E + e]], 1);
}

__global__ void ps1_kernel(const int* __restrict__ deg, int* __restrict__ chunkSum, int N) {
    __shared__ int sm[CHUNK];
    int i = blockIdx.x * CHUNK + threadIdx.x;
    sm[threadIdx.x] = (i < N) ? deg[i] : 0;
    __syncthreads();
    for (int off = CHUNK / 2; off > 0; off >>= 1) {
        if (threadIdx.x < off) sm[threadIdx.x] += sm[threadIdx.x + off];
        __syncthreads();
    }
    if (threadIdx.x == 0) chunkSum[blockIdx.x] = sm[0];
}

__global__ void ps2_kernel(const int* __restrict__ chunkSum, int* __restrict__ chunkOff,
                           int nc, int* __restrict__ offs, int N, int E) {
    __shared__ int sm[CHUNK];
    int t = threadIdx.x;
    int own = (t < nc) ? chunkSum[t] : 0;
    sm[t] = own;
    for (int off = 1; off < CHUNK; off <<= 1) {
        __syncthreads();
        int v = (t >= off) ? sm[t - off] : 0;
        __syncthreads();
        sm[t] += v;
    }
    if (t < nc) chunkOff[t] = sm[t] - own;
    if (t == 0) offs[N] = E;
}

__global__ void ps3_kernel(const int* __restrict__ deg, const int* __restrict__ chunkOff,
                           int* __restrict__ offs, int* __restrict__ cursor, int N) {
    __shared__ int sm[CHUNK];
    int t = threadIdx.x;
    int i = blockIdx.x * CHUNK + t;
    int own = (i < N) ? deg[i] : 0;
    sm[t] = own;
    for (int off = 1; off < CHUNK; off <<= 1) {
        __syncthreads();
        int v = (t >= off) ? sm[t - off] : 0;
        __syncthreads();
        sm[t] += v;
    }
    if (i < N) {
        int o = chunkOff[blockIdx.x] + sm[t] - own;
        offs[i] = o;
        cursor[i] = o;
    }
}

__global__ void fill_kernel(const int* __restrict__ ei, int* __restrict__ cursor,
                            int* __restrict__ srcl, int E) {
    int e = blockIdx.x * blockDim.x + threadIdx.x;
    if (e >= E) return;
    int s = ei[e];
    int d = ei[(size_t)E + e];
    int pos = atomicAdd(&cursor[d], 1);
    srcl[pos] = s;
}

// ---------------- W transpose (both weight sets in one launch) ----------------
__global__ void transpose_w_kernel(const float* __restrict__ W1, const float* __restrict__ W2,
                                   unsigned short* __restrict__ Wt1, unsigned short* __restrict__ Wt2,
                                   int perSet) {
    __shared__ float tile[32][33];
    int id = blockIdx.x;
    const float* W = W1;
    unsigned short* Wt = Wt1;
    if (id >= perSet) { W = W2; Wt = Wt2; id -= perSet; }
    int mat = id >> 6, t = id & 63;
    int kt = (t >> 3) * 32, nt = (t & 7) * 32;
    const float* Wm = W + (size_t)mat * HH * HH;
    unsigned short* Wtm = Wt + (size_t)mat * HH * HH;
    int lx = threadIdx.x & 31, ly = threadIdx.x >> 5;
#pragma unroll
    for (int yy = 0; yy < 32; yy += 8)
        tile[ly + yy][lx] = Wm[(size_t)(kt + ly + yy) * HH + nt + lx];
    __syncthreads();
#pragma unroll
    for (int yy = 0; yy < 32; yy += 8)
        Wtm[(size_t)(nt + ly + yy) * HH + kt + lx] = f2h(tile[lx][ly + yy]);
}

// ---------------- fused aggregation: z[n] = t(x[n]) + sum t(x[src_j]) ----------------
// 1 node/wave, 64 lanes x ushort4 per row, uniform j; 4 independent gathers in flight.
__global__ __launch_bounds__(256) void aggregate_fused_kernel(
        const unsigned short* __restrict__ h,
        const int* __restrict__ offs, const int* __restrict__ srcl,
        const float* __restrict__ stats, const float* __restrict__ gv,
        const float* __restrict__ bv, float invM,
        unsigned short* __restrict__ z, int N) {
    int n = blockIdx.x * 4 + (threadIdx.x >> 6);
    int l = threadIdx.x & 63;
    if (n >= N) return;
    int c = l * 4;
    const bool apply = (stats != nullptr);
    float sc0 = 1.f, sc1 = 1.f, sc2 = 1.f, sc3 = 1.f;
    float sh0 = 0.f, sh1 = 0.f, sh2 = 0.f, sh3 = 0.f;
    if (apply) {
        bn_derive(stats, gv, bv, invM, c + 0, sc0, sh0);
        bn_derive(stats, gv, bv, invM, c + 1, sc1, sh1);
        bn_derive(stats, gv, bv, invM, c + 2, sc2, sh2);
        bn_derive(stats, gv, bv, invM, c + 3, sc3, sh3);
    }

#define LOADT(row, r0, r1, r2, r3)                                      \
    {                                                                   \
        ushort4 v_ = *(const ushort4*)&h[(size_t)(row) * HH + c];       \
        r0 = h2f(v_.x); r1 = h2f(v_.y); r2 = h2f(v_.z); r3 = h2f(v_.w); \
        if (apply) {                                                    \
            r0 = fmaxf(r0 * sc0 + sh0, 0.f);                            \
            r1 = fmaxf(r1 * sc1 + sh1, 0.f);                            \
            r2 = fmaxf(r2 * sc2 + sh2, 0.f);                            \
            r3 = fmaxf(r3 * sc3 + sh3, 0.f);                            \
        }                                                               \
    }

    float a0, a1, a2, a3;
    LOADT(n, a0, a1, a2, a3);                   // self term
    int s0 = offs[n], s1 = offs[n + 1];
    int j = s0;
    for (; j + 4 <= s1; j += 4) {
        int r0 = srcl[j], r1 = srcl[j + 1], r2 = srcl[j + 2], r3 = srcl[j + 3];
        float t0, t1, t2, t3, u0, u1, u2, u3;
        float p0, p1, p2, p3, q0, q1, q2, q3;
        LOADT(r0, t0, t1, t2, t3);
        LOADT(r1, u0, u1, u2, u3);
        LOADT(r2, p0, p1, p2, p3);
        LOADT(r3, q0, q1, q2, q3);
        a0 += (t0 + u0) + (p0 + q0);
        a1 += (t1 + u1) + (p1 + q1);
        a2 += (t2 + u2) + (p2 + q2);
        a3 += (t3 + u3) + (p3 + q3);
    }
    for (; j < s1; ++j) {
        float t0, t1, t2, t3;
        LOADT(srcl[j], t0, t1, t2, t3);
        a0 += t0; a1 += t1; a2 += t2; a3 += t3;
    }
#undef LOADT
    ushort4 o;
    o.x = f2h(a0); o.y = f2h(a1); o.z = f2h(a2); o.w = f2h(a3);
    *(ushort4*)&z[(size_t)n * HH + c] = o;
}

// ---------------- f16 MFMA GEMM, templated on A-side BN fusion ----------------
// Tile 128x128, BK=64, 4 waves (2x2). 1D grid (2*nRow) with a BIJECTIVE
// XCD-pair swizzle: within each 16-id group, ids r and r+8 are the two
// col-halves of the same A-row-tile and land on the SAME XCD (linear id
// round-robins XCDs) -> A's 2nd read is an L2 hit. Tail (nRow%8) handled
// explicitly (ERRATA #11).
// BN=true applies relu(x*sc+sh) to A FRAGMENTS after ds_read (k-slice is
// m-independent). Epilogue: bias + out-stats with cross-wave LDS combine
// (halves global atomics) + LDS-staged coalesced C stores.
template <bool BN>
__global__ __launch_bounds__(256) void mfma_gemm_t(const unsigned short* __restrict__ A,
                                                   const unsigned short* __restrict__ Wt,
                                                   const float* __restrict__ bias,
                                                   unsigned short* __restrict__ C,
                                                   float* __restrict__ stats,
                                                   const float* __restrict__ bnstats,
                                                   const float* __restrict__ gv,
                                                   const float* __restrict__ bv,
                                                   float invM, int M) {
    __shared__ unsigned short sm[128 * 136];   // staging: [0,16384); epilogue: whole
    __shared__ __align__(16) _Float16 lsc[256];
    __shared__ __align__(16) _Float16 lsh[256];
    __shared__ float sred[256];                // cross-wave stats combine (128 cols x {s,s2})
    unsigned short* As = sm;
    unsigned short* Bs = sm + 128 * 64;
    int tid = threadIdx.x;
    int w = tid >> 6, l = tid & 63;
    int wr = w >> 1, wc = w & 1;

    // bijective XCD-pair block swizzle
    int nRow = (M + 127) >> 7;
    int fullIds = (nRow & ~7) * 2;     // 16 * (nRow/8)
    int id = blockIdx.x;
    int p, cc;
    if (id < fullIds) {
        int gq = id >> 4, r = id & 15;
        cc = r >> 3;
        p = gq * 8 + (r & 7);
    } else {
        int t = id - fullIds;
        p = (nRow & ~7) + (t >> 1);
        cc = t & 1;
    }
    int row0 = p * 128;
    int col0 = cc * 128;

    int g = (l & 7) ^ (l >> 3);      // pre-swizzled source granule
    int srow = w * 8 + (l >> 3);

    if (BN) {
        float sc, sh;
        bn_derive(bnstats, gv, bv, invM, tid, sc, sh);
        lsc[tid] = (_Float16)sc;
        lsh[tid] = (_Float16)sh;
        __syncthreads();
    }

    f32x4 acc[4][4] = {};

    const unsigned short* AB = A + (size_t)row0 * HH;
    const unsigned short* WB = Wt + (size_t)col0 * HH;

    for (int k0 = 0; k0 < 256; k0 += 64) {
#pragma unroll
        for (int r = 0; r < 4; ++r) {
            int row = r * 32 + srow;
            size_t go = (size_t)row * HH + k0 + g * 8;
            int lo = (r * 32 + w * 8) * 64;
            gload16(AB + go, &As[lo]);
            gload16(WB + go, &Bs[lo]);
        }
        __syncthreads();
#pragma unroll
        for (int kh = 0; kh < 2; ++kh) {
            f16x8 af[4], bf[4];
            f16x8 scv, shv;
            if (BN) {
                int kb = k0 + (kh * 4 + (l >> 4)) * 8;
                scv = *(const f16x8*)&lsc[kb];
                shv = *(const f16x8*)&lsh[kb];
            }
#pragma unroll
            for (int m = 0; m < 4; ++m) {
                int rr = wr * 64 + m * 16 + (l & 15);
                int gs = (kh * 4 + (l >> 4)) ^ (rr & 7);
                af[m] = *(const f16x8*)&As[rr * 64 + gs * 8];
                if (BN) {
                    af[m] = af[m] * scv + shv;
                    af[m] = __builtin_elementwise_max(af[m], (f16x8)(_Float16)0);
                }
            }
#pragma unroll
            for (int n = 0; n < 4; ++n) {
                int rr = wc * 64 + n * 16 + (l & 15);
                int gs = (kh * 4 + (l >> 4)) ^ (rr & 7);
                bf[n] = *(const f16x8*)&Bs[rr * 64 + gs * 8];
            }
#pragma unroll
            for (int m = 0; m < 4; ++m)
#pragma unroll
                for (int n = 0; n < 4; ++n)
                    acc[m][n] = __builtin_amdgcn_mfma_f32_16x16x32_f16(af[m], bf[n], acc[m][n], 0, 0, 0);
        }
        __syncthreads();
    }

    // epilogue: bias + C-tile to LDS + per-wave stats accumulation (registers)
    int mvalid = M - row0;
    float sv[4], s2v[4];
#pragma unroll
    for (int n = 0; n < 4; ++n) {
        int colr = wc * 64 + n * 16 + (l & 15);
        float bvv = bias[col0 + colr];
        float s = 0.f, s2 = 0.f;
#pragma unroll
        for (int m = 0; m < 4; ++m) {
            int rb = wr * 64 + m * 16 + (l >> 4) * 4;
#pragma unroll
            for (int r = 0; r < 4; ++r) {
                float v = acc[m][n][r] + bvv;
                sm[(rb + r) * 136 + colr] = f2h(v);
                if (rb + r < mvalid) { s += v; s2 += v * v; }
            }
        }
        s += __shfl_xor(s, 16);   s += __shfl_xor(s, 32);
        s2 += __shfl_xor(s2, 16); s2 += __shfl_xor(s2, 32);
        sv[n] = s;
        s2v[n] = s2;
    }
    // wr=1 deposits partials; wr=0 combines -> one atomic per col per stat
    if (wr == 1 && (l >> 4) == 0) {
#pragma unroll
        for (int n = 0; n < 4; ++n) {
            int colr = wc * 64 + n * 16 + (l & 15);
            sred[colr] = sv[n];
            sred[128 + colr] = s2v[n];
        }
    }
    __syncthreads();   // covers sred AND the sm C-tile
    if (wr == 0 && (l >> 4) == 0) {
#pragma unroll
        for (int n = 0; n < 4; ++n) {
            int colr = wc * 64 + n * 16 + (l & 15);
            atomicAdd(&stats[col0 + colr], sv[n] + sred[colr]);
            atomicAdd(&stats[HH + col0 + colr], s2v[n] + sred[128 + colr]);
        }
    }
#pragma unroll
    for (int i = 0; i < 8; ++i) {
        int ci = i * 256 + tid;          // 0..2047 chunk id
        int row = ci >> 4;
        int cq = (ci & 15) * 8;
        if (row0 + row < M) {
            uint4 v = *(const uint4*)&sm[row * 136 + cq];
            *(uint4*)&C[(size_t)(row0 + row) * HH + col0 + cq] = v;
        }
    }
}

// ---------------- BN helpers (classifier path) ----------------
__global__ void bn_stats_kernel(const float* __restrict__ X, int M, float* __restrict__ stats) {
    int c = threadIdx.x;
    int r0 = blockIdx.x * 128;
    int r1 = min(r0 + 128, M);
    float s = 0.f, s2 = 0.f;
    for (int r = r0; r < r1; ++r) {
        float v = X[(size_t)r * HH + c];
        s += v;
        s2 += v * v;
    }
    atomicAdd(&stats[c], s);
    atomicAdd(&stats[HH + c], s2);
}

__global__ void bn_finalize_kernel(float* __restrict__ stats, const float* __restrict__ g,
                                   const float* __restrict__ b, float invM) {
    int c = threadIdx.x;
    float sc, sh;
    bn_derive(stats, g, b, invM, c, sc, sh);
    stats[2 * HH + c] = sc;
    stats[3 * HH + c] = sh;
}

__global__ void bn_apply_relu_kernel(float* __restrict__ X, int n4, const float* __restrict__ stats) {
    int i = blockIdx.x * blockDim.x + threadIdx.x;
    int stride = gridDim.x * blockDim.x;
    for (; i < n4; i += stride) {
        int c4 = (i & 63) * 4;
        float4 v = ((float4*)X)[i];
        float4 sc = *(const float4*)&stats[2 * HH + c4];
        float4 sh = *(const float4*)&stats[3 * HH + c4];
        v.x = fmaxf(v.x * sc.x + sh.x, 0.f);
        v.y = fmaxf(v.y * sc.y + sh.y, 0.f);
        v.z = fmaxf(v.z * sc.z + sh.z, 0.f);
        v.w = fmaxf(v.w * sc.w + sh.w, 0.f);
        ((float4*)X)[i] = v;
    }
}

// ---------------- f32 GEMM (classifier only) ----------------
__global__ __launch_bounds__(256) void gemm_kernel(const float* __restrict__ A,
                                                   const float* __restrict__ W,
                                                   const float* __restrict__ bias,
                                                   float* __restrict__ C,
                                                   int M, int ldw) {
    __shared__ float Asm[64][33];
    __shared__ float Wsm[32][64];
    int tid = threadIdx.x;
    int tx = tid & 15, ty = tid >> 4;
    int row0 = blockIdx.x * 64;
    int col0 = blockIdx.y * 64;
    float acc[4][4] = {};

    for (int k0 = 0; k0 < 256; k0 += 32) {
#pragma unroll
        for (int t = 0; t < 2; ++t) {
            int s = tid + t * 256;
            int m = s >> 3;
            int kq = (s & 7) * 4;
            float4 v = make_float4(0.f, 0.f, 0.f, 0.f);
            if (row0 + m < M) v = *(const float4*)&A[(size_t)(row0 + m) * 256 + k0 + kq];
            Asm[m][kq + 0] = v.x; Asm[m][kq + 1] = v.y; Asm[m][kq + 2] = v.z; Asm[m][kq + 3] = v.w;
        }
#pragma unroll
        for (int t = 0; t < 2; ++t) {
            int s = tid + t * 256;
            int kk = s >> 4;
            int cq = (s & 15) * 4;
            *(float4*)&Wsm[kk][cq] = *(const float4*)&W[(size_t)(k0 + kk) * ldw + col0 + cq];
        }
        __syncthreads();
#pragma unroll
        for (int kk = 0; kk < 32; ++kk) {
            float a0 = Asm[ty * 4 + 0][kk];
            float a1 = Asm[ty * 4 + 1][kk];
            float a2 = Asm[ty * 4 + 2][kk];
            float a3 = Asm[ty * 4 + 3][kk];
            float4 wv = *(const float4*)&Wsm[kk][tx * 4];
            acc[0][0] += a0 * wv.x; acc[0][1] += a0 * wv.y; acc[0][2] += a0 * wv.z; acc[0][3] += a0 * wv.w;
            acc[1][0] += a1 * wv.x; acc[1][1] += a1 * wv.y; acc[1][2] += a1 * wv.z; acc[1][3] += a1 * wv.w;
            acc[2][0] += a2 * wv.x; acc[2][1] += a2 * wv.y; acc[2][2] += a2 * wv.z; acc[2][3] += a2 * wv.w;
            acc[3][0] += a3 * wv.x; acc[3][1] += a3 * wv.y; acc[3][2] += a3 * wv.z; acc[3][3] += a3 * wv.w;
        }
        __syncthreads();
    }

    float4 bvv = *(const float4*)&bias[col0 + tx * 4];
#pragma unroll
    for (int j = 0; j < 4; ++j) {
        int row = row0 + ty * 4 + j;
        if (row < M) {
            float4 o = make_float4(acc[j][0] + bvv.x, acc[j][1] + bvv.y,
                                   acc[j][2] + bvv.z, acc[j][3] + bvv.w);
            *(float4*)&C[(size_t)row * ldw + col0 + tx * 4] = o;
        }
    }
}

// ---------------- fused mean pool: pooled = mean relu(bn(z2_last)) ----------------
__device__ __forceinline__ int lbound(const int* a, int n, int v) {
    int lo = 0, hi = n;
    while (lo < hi) {
        int mid = (lo + hi) >> 1;
        if (a[mid] < v) lo = mid + 1; else hi = mid;
    }
    return lo;
}

__global__ void pool_fused_kernel(const unsigned short* __restrict__ Hm,
                                  const int* __restrict__ batch,
                                  const float* __restrict__ stats,
                                  const float* __restrict__ gv,
                                  const float* __restrict__ bv, float invM,
                                  int N, float* __restrict__ pooled) {
    int g = blockIdx.x;
    int c = threadIdx.x;
    int s = lbound(batch, N, g);
    int e = lbound(batch, N, g + 1);
    float sc, sh;
    bn_derive(stats, gv, bv, invM, c, sc, sh);
    float acc = 0.f;
    for (int r = s; r < e; ++r)
        acc += fmaxf(h2f(Hm[(size_t)r * HH + c]) * sc + sh, 0.f);
    pooled[(size_t)g * HH + c] = acc / (float)max(e - s, 1);
}

// ---------------- launch ----------------
extern "C" void kernel_launch(void* const* d_in, const int* in_sizes, int n_in,
                              void* d_out, int out_size, void* d_ws, size_t ws_size,
                              hipStream_t stream) {
    const float* x_atom = (const float*)d_in[0];
    const float* x_pe   = (const float*)d_in[1];
    const int* ei       = (const int*)d_in[2];
    const int* batch    = (const int*)d_in[3];
    const float* ae_w = (const float*)d_in[4];
    const float* ae_b = (const float*)d_in[5];
    const float* pe_w = (const float*)d_in[6];
    const float* pe_b = (const float*)d_in[7];
    const float* w1  = (const float*)d_in[8];
    const float* b1  = (const float*)d_in[9];
    const float* g1  = (const float*)d_in[10];
    const float* be1 = (const float*)d_in[11];
    const float* w2  = (const float*)d_in[12];
    const float* b2  = (const float*)d_in[13];
    const float* bng = (const float*)d_in[14];
    const float* bnb = (const float*)d_in[15];
    const float* cl1_w = (const float*)d_in[16];
    const float* cl1_b = (const float*)d_in[17];
    const float* clg = (const float*)d_in[18];
    const float* clb = (const float*)d_in[19];
    const float* cl2_w = (const float*)d_in[20];
    const float* cl2_b = (const float*)d_in[21];

    const int N = in_sizes[3];
    const int E = in_sizes[2] / 2;
    const int T = in_sizes[21];
    const int B = out_size / T;
    const int Lnum = in_sizes[9] / HH;
    const int nc = cdiv(N, CHUNK);
    const int Npad = cdiv(N, 128) * 128;
    const size_t P = (size_t)Npad * HH;

    unsigned short* X = (unsigned short*)d_ws;
    unsigned short* Y = X + P;
    unsigned short* wt1 = Y + P;                        // L*HH*HH f16
    unsigned short* wt2 = wt1 + (size_t)Lnum * HH * HH;
    float* stats = (float*)(wt2 + (size_t)Lnum * HH * HH);   // NSLOT x 4*HH
    float* pooled = stats + (size_t)NSLOT * 4 * HH;
    float* zc = pooled + (size_t)B * HH;
    int* deg = (int*)(zc + (size_t)B * HH);
    int* offs = deg + N;
    int* cursor = offs + N + 1;
    int* chunkSum = cursor + N;
    int* chunkOff = chunkSum + 256;
    int* srcl = chunkOff + 256;

    const int BH4 = B * (HH / 4);
    const float invN = 1.f / (float)N;

    // ---- setup (deg + stats zero, one launch) ----
    setup_kernel<<<cdiv(max(N, NSLOT * 512), 256), 256, 0, stream>>>(deg, N, stats);

    // ---- CSR build ----
    hist_kernel<<<cdiv(E, 256), 256, 0, stream>>>(ei, deg, E);
    ps1_kernel<<<nc, CHUNK, 0, stream>>>(deg, chunkSum, N);
    ps2_kernel<<<1, CHUNK, 0, stream>>>(chunkSum, chunkOff, nc, offs, N, E);
    ps3_kernel<<<nc, CHUNK, 0, stream>>>(deg, chunkOff, offs, cursor, N);
    fill_kernel<<<cdiv(E, 256), 256, 0, stream>>>(ei, cursor, srcl, E);

    // ---- weight transpose (both sets, one launch) ----
    transpose_w_kernel<<<2 * Lnum * 64, 256, 0, stream>>>(w1, w2, wt1, wt2, Lnum * 64);

    // ---- embed ----
    embed_kernel<<<N, HH, 0, stream>>>(x_atom, x_pe, ae_w, ae_b, pe_w, pe_b, X, N);

    const int nRow = cdiv(N, 128);
    const int mf_blocks = 2 * nRow;   // 1D grid, XCD-pair swizzle inside

    unsigned short *in = X, *ot = Y;

    for (int i = 0; i < Lnum; ++i) {
        float* slot1 = stats + (size_t)(2 * i) * 4 * HH;
        float* slot2 = stats + (size_t)(2 * i + 1) * 4 * HH;
        const float* aggStats = (i == 0) ? nullptr : stats + (size_t)(2 * i - 1) * 4 * HH;
        const float* aggG = (i == 0) ? nullptr : bng + (size_t)(i - 1) * HH;
        const float* aggB = (i == 0) ? nullptr : bnb + (size_t)(i - 1) * HH;

        // z = t(in) + gather-sum t(in[src]) : in -> ot
        aggregate_fused_kernel<<<cdiv(N, 4), 256, 0, stream>>>(in, offs, srcl,
                                                               aggStats, aggG, aggB, invN, ot, N);

        // z1 = z @ w1 + b1 : ot -> in (raw z1; inner BN applied in GEMM2 fragments)
        mfma_gemm_t<false><<<mf_blocks, 256, 0, stream>>>(ot, wt1 + (size_t)i * HH * HH,
                                                          b1 + (size_t)i * HH, in, slot1,
                                                          nullptr, nullptr, nullptr, 0.f, N);

        // z2 = relu(bn(z1)) @ w2 + b2 : in -> ot (BN on A fragments, async staging kept)
        mfma_gemm_t<true><<<mf_blocks, 256, 0, stream>>>(in, wt2 + (size_t)i * HH * HH,
                                                         b2 + (size_t)i * HH, ot, slot2,
                                                         slot1, g1 + (size_t)i * HH,
                                                         be1 + (size_t)i * HH, invN, N);

        unsigned short* t = in; in = ot; ot = t;
    }

    // ---- fused mean pool (applies last outer BN+relu) ----
    pool_fused_kernel<<<B, HH, 0, stream>>>(in, batch,
                                            stats + (size_t)(2 * Lnum - 1) * 4 * HH,
                                            bng + (size_t)(Lnum - 1) * HH,
                                            bnb + (size_t)(Lnum - 1) * HH, invN, N, pooled);

    // ---- classifier (f32 path, slot 10) ----
    float* slotC = stats + (size_t)10 * 4 * HH;
    dim3 cls_grid1(cdiv(B, 64), HH / 64);
    gemm_kernel<<<cls_grid1, 256, 0, stream>>>(pooled, cl1_w, cl1_b, zc, B, HH);
    bn_stats_kernel<<<cdiv(B, 128), HH, 0, stream>>>(zc, B, slotC);
    bn_finalize_kernel<<<1, HH, 0, stream>>>(slotC, clg, clb, 1.f / B);
    bn_apply_relu_kernel<<<min(2048, cdiv(BH4, 256)), 256, 0, stream>>>(zc, BH4, slotC);

    dim3 cls_grid2(cdiv(B, 64), T / 64);
    gemm_kernel<<<cls_grid2, 256, 0, stream>>>(zc, cl2_w, cl2_b, (float*)d_out, B, T);
}

// Round 13
// 843.802 us; speedup vs baseline: 1.8561x; 1.0530x over previous
//
#include <hip/hip_runtime.h>
#include <hip/hip_bf16.h>
#include <stdint.h>

#define HH 256
#define BN_EPS 1e-5f
#define CHUNK 256
#define NSLOT 12   // stats slots: layer i -> 2i (inner), 2i+1 (outer); classifier -> 10

static inline int cdiv(int a, int b) { return (a + b - 1) / b; }

typedef _Float16 f16x8 __attribute__((ext_vector_type(8)));
typedef __attribute__((ext_vector_type(4))) float f32x4;

__device__ __forceinline__ unsigned short f2h(float f) {
    _Float16 h = (_Float16)f;            // v_cvt_f16_f32, RNE
    unsigned short u;
    __builtin_memcpy(&u, &h, 2);
    return u;
}
__device__ __forceinline__ float h2f(unsigned short u) {
    _Float16 h;
    __builtin_memcpy(&h, &u, 2);
    return (float)h;
}

__device__ __forceinline__ void gload16(const void* g, void* lds) {
    __builtin_amdgcn_global_load_lds((const __attribute__((address_space(1))) unsigned int*)g,
                                     (__attribute__((address_space(3))) unsigned int*)lds, 16, 0, 0);
}

// derive BN scale/shift for one channel from raw sums
__device__ __forceinline__ void bn_derive(const float* __restrict__ stats, const float* __restrict__ g,
                                          const float* __restrict__ b, float invM, int c,
                                          float& sc, float& sh) {
    float mu = stats[c] * invM;
    float var = stats[HH + c] * invM - mu * mu;
    float rstd = rsqrtf(var + BN_EPS);
    sc = rstd * g[c];
    sh = b[c] - mu * sc;
}

// ---------------- embed -> f16 (wave per node) ----------------
__global__ __launch_bounds__(256) void embed_kernel(const float* __restrict__ xa,
                                                    const float* __restrict__ xp,
                                                    const float* __restrict__ aw,
                                                    const float* __restrict__ ab,
                                                    const float* __restrict__ pw,
                                                    const float* __restrict__ pb,
                                                    unsigned short* __restrict__ h, int N) {
    int n = blockIdx.x * 4 + (threadIdx.x >> 6);
    int l = threadIdx.x & 63;
    if (n >= N) return;
    int c = l * 4;
    float4 abv = *(const float4*)&ab[c];
    float4 pbv = *(const float4*)&pb[c];
    float a0 = abv.x + pbv.x, a1 = abv.y + pbv.y, a2 = abv.z + pbv.z, a3 = abv.w + pbv.w;
#pragma unroll
    for (int k = 0; k < 9; ++k) {
        float xv = xa[n * 9 + k];                       // wave-uniform
        float4 w = *(const float4*)&aw[k * HH + c];
        a0 += xv * w.x; a1 += xv * w.y; a2 += xv * w.z; a3 += xv * w.w;
    }
#pragma unroll
    for (int k = 0; k < 8; ++k) {
        float xv = xp[n * 8 + k];                       // wave-uniform
        float4 w = *(const float4*)&pw[k * HH + c];
        a0 += xv * w.x; a1 += xv * w.y; a2 += xv * w.z; a3 += xv * w.w;
    }
    ushort4 o;
    o.x = f2h(a0); o.y = f2h(a1); o.z = f2h(a2); o.w = f2h(a3);
    *(ushort4*)&h[(size_t)n * HH + c] = o;
}

// ---------------- setup: zero deg[N] + zero stats sums (one launch) ----------------
__global__ void setup_kernel(int* __restrict__ deg, int N, float* __restrict__ stats) {
    int i = blockIdx.x * blockDim.x + threadIdx.x;
    if (i < N) deg[i] = 0;
    if (i < NSLOT * 512) {
        int slot = i >> 9;
        stats[(size_t)slot * 4 * HH + (i & 511)] = 0.f;
    }
}

// ---------------- CSR build ----------------
__global__ void hist_kernel(const int* __restrict__ ei, int* __restrict__ deg, int E) {
    int e = blockIdx.x * blockDim.x + threadIdx.x;
    if (e < E) atomicAdd(&deg[ei[(size_t)E + e]], 1);
}

__global__ void ps1_kernel(const int* __restrict__ deg, int* __restrict__ chunkSum, int N) {
    __shared__ int sm[CHUNK];
    int i = blockIdx.x * CHUNK + threadIdx.x;
    sm[threadIdx.x] = (i < N) ? deg[i] : 0;
    __syncthreads();
    for (int off = CHUNK / 2; off > 0; off >>= 1) {
        if (threadIdx.x < off) sm[threadIdx.x] += sm[threadIdx.x + off];
        __syncthreads();
    }
    if (threadIdx.x == 0) chunkSum[blockIdx.x] = sm[0];
}

__global__ void ps2_kernel(const int* __restrict__ chunkSum, int* __restrict__ chunkOff,
                           int nc, int* __restrict__ offs, int N, int E) {
    __shared__ int sm[CHUNK];
    int t = threadIdx.x;
    int own = (t < nc) ? chunkSum[t] : 0;
    sm[t] = own;
    for (int off = 1; off < CHUNK; off <<= 1) {
        __syncthreads();
        int v = (t >= off) ? sm[t - off] : 0;
        __syncthreads();
        sm[t] += v;
    }
    if (t < nc) chunkOff[t] = sm[t] - own;
    if (t == 0) offs[N] = E;
}

__global__ void ps3_kernel(const int* __restrict__ deg, const int* __restrict__ chunkOff,
                           int* __restrict__ offs, int* __restrict__ cursor, int N) {
    __shared__ int sm[CHUNK];
    int t = threadIdx.x;
    int i = blockIdx.x * CHUNK + t;
    int own = (i < N) ? deg[i] : 0;
    sm[t] = own;
    for (int off = 1; off < CHUNK; off <<= 1) {
        __syncthreads();
        int v = (t >= off) ? sm[t - off] : 0;
        __syncthreads();
        sm[t] += v;
    }
    if (i < N) {
        int o = chunkOff[blockIdx.x] + sm[t] - own;
        offs[i] = o;
        cursor[i] = o;
    }
}

__global__ void fill_kernel(const int* __restrict__ ei, int* __restrict__ cursor,
                            int* __restrict__ srcl, int E) {
    int e = blockIdx.x * blockDim.x + threadIdx.x;
    if (e >= E) return;
    int s = ei[e];
    int d = ei[(size_t)E + e];
    int pos = atomicAdd(&cursor[d], 1);
    srcl[pos] = s;
}

// ---------------- W transpose (both weight sets in one launch) ----------------
__global__ void transpose_w_kernel(const float* __restrict__ W1, const float* __restrict__ W2,
                                   unsigned short* __restrict__ Wt1, unsigned short* __restrict__ Wt2,
                                   int perSet) {
    __shared__ float tile[32][33];
    int id = blockIdx.x;
    const float* W = W1;
    unsigned short* Wt = Wt1;
    if (id >= perSet) { W = W2; Wt = Wt2; id -= perSet; }
    int mat = id >> 6, t = id & 63;
    int kt = (t >> 3) * 32, nt = (t & 7) * 32;
    const float* Wm = W + (size_t)mat * HH * HH;
    unsigned short* Wtm = Wt + (size_t)mat * HH * HH;
    int lx = threadIdx.x & 31, ly = threadIdx.x >> 5;
#pragma unroll
    for (int yy = 0; yy < 32; yy += 8)
        tile[ly + yy][lx] = Wm[(size_t)(kt + ly + yy) * HH + nt + lx];
    __syncthreads();
#pragma unroll
    for (int yy = 0; yy < 32; yy += 8)
        Wtm[(size_t)(nt + ly + yy) * HH + kt + lx] = f2h(tile[lx][ly + yy]);
}

// ---------------- fused aggregation: z[n] = t(x[n]) + sum t(x[src_j]) ----------------
// 1 node/wave, 64 lanes x ushort4 per row, uniform j; 8 independent gathers in flight.
__global__ __launch_bounds__(256) void aggregate_fused_kernel(
        const unsigned short* __restrict__ h,
        const int* __restrict__ offs, const int* __restrict__ srcl,
        const float* __restrict__ stats, const float* __restrict__ gv,
        const float* __restrict__ bv, float invM,
        unsigned short* __restrict__ z, int N) {
    int n = blockIdx.x * 4 + (threadIdx.x >> 6);
    int l = threadIdx.x & 63;
    if (n >= N) return;
    int c = l * 4;
    const bool apply = (stats != nullptr);
    float sc0 = 1.f, sc1 = 1.f, sc2 = 1.f, sc3 = 1.f;
    float sh0 = 0.f, sh1 = 0.f, sh2 = 0.f, sh3 = 0.f;
    if (apply) {
        bn_derive(stats, gv, bv, invM, c + 0, sc0, sh0);
        bn_derive(stats, gv, bv, invM, c + 1, sc1, sh1);
        bn_derive(stats, gv, bv, invM, c + 2, sc2, sh2);
        bn_derive(stats, gv, bv, invM, c + 3, sc3, sh3);
    }

#define LOADT(row, r0, r1, r2, r3)                                      \
    {                                                                   \
        ushort4 v_ = *(const ushort4*)&h[(size_t)(row) * HH + c];       \
        r0 = h2f(v_.x); r1 = h2f(v_.y); r2 = h2f(v_.z); r3 = h2f(v_.w); \
        if (apply) {                                                    \
            r0 = fmaxf(r0 * sc0 + sh0, 0.f);                            \
            r1 = fmaxf(r1 * sc1 + sh1, 0.f);                            \
            r2 = fmaxf(r2 * sc2 + sh2, 0.f);                            \
            r3 = fmaxf(r3 * sc3 + sh3, 0.f);                            \
        }                                                               \
    }

    float a0, a1, a2, a3;
    LOADT(n, a0, a1, a2, a3);                   // self term
    int s0 = offs[n], s1 = offs[n + 1];
    int j = s0;
    for (; j + 8 <= s1; j += 8) {
        int r0 = srcl[j], r1 = srcl[j + 1], r2 = srcl[j + 2], r3 = srcl[j + 3];
        int r4 = srcl[j + 4], r5 = srcl[j + 5], r6 = srcl[j + 6], r7 = srcl[j + 7];
        float t0[4], t1[4], t2[4], t3[4], t4[4], t5[4], t6[4], t7[4];
        LOADT(r0, t0[0], t0[1], t0[2], t0[3]);
        LOADT(r1, t1[0], t1[1], t1[2], t1[3]);
        LOADT(r2, t2[0], t2[1], t2[2], t2[3]);
        LOADT(r3, t3[0], t3[1], t3[2], t3[3]);
        LOADT(r4, t4[0], t4[1], t4[2], t4[3]);
        LOADT(r5, t5[0], t5[1], t5[2], t5[3]);
        LOADT(r6, t6[0], t6[1], t6[2], t6[3]);
        LOADT(r7, t7[0], t7[1], t7[2], t7[3]);
        a0 += ((t0[0] + t1[0]) + (t2[0] + t3[0])) + ((t4[0] + t5[0]) + (t6[0] + t7[0]));
        a1 += ((t0[1] + t1[1]) + (t2[1] + t3[1])) + ((t4[1] + t5[1]) + (t6[1] + t7[1]));
        a2 += ((t0[2] + t1[2]) + (t2[2] + t3[2])) + ((t4[2] + t5[2]) + (t6[2] + t7[2]));
        a3 += ((t0[3] + t1[3]) + (t2[3] + t3[3])) + ((t4[3] + t5[3]) + (t6[3] + t7[3]));
    }
    for (; j + 4 <= s1; j += 4) {
        int r0 = srcl[j], r1 = srcl[j + 1], r2 = srcl[j + 2], r3 = srcl[j + 3];
        float t0[4], t1[4], t2[4], t3[4];
        LOADT(r0, t0[0], t0[1], t0[2], t0[3]);
        LOADT(r1, t1[0], t1[1], t1[2], t1[3]);
        LOADT(r2, t2[0], t2[1], t2[2], t2[3]);
        LOADT(r3, t3[0], t3[1], t3[2], t3[3]);
        a0 += (t0[0] + t1[0]) + (t2[0] + t3[0]);
        a1 += (t0[1] + t1[1]) + (t2[1] + t3[1]);
        a2 += (t0[2] + t1[2]) + (t2[2] + t3[2]);
        a3 += (t0[3] + t1[3]) + (t2[3] + t3[3]);
    }
    for (; j < s1; ++j) {
        float t0, t1, t2, t3;
        LOADT(srcl[j], t0, t1, t2, t3);
        a0 += t0; a1 += t1; a2 += t2; a3 += t3;
    }
#undef LOADT
    ushort4 o;
    o.x = f2h(a0); o.y = f2h(a1); o.z = f2h(a2); o.w = f2h(a3);
    *(ushort4*)&z[(size_t)n * HH + c] = o;
}

// ---------------- f16 MFMA GEMM, templated on A-side BN fusion ----------------
// Tile 128x128, BK=64, 4 waves (2x2). 1D grid (2*nRow) with a BIJECTIVE
// XCD-pair swizzle (ids r and r+8 in each 16-group share the A-row-tile and
// land on the same XCD -> A's 2nd read is an L2 hit; tail explicit).
// BN=true applies relu(x*sc+sh) to A FRAGMENTS after ds_read.
// Epilogue: bias + out-stats (cross-wave LDS combine) + LDS-staged C stores.
template <bool BN>
__global__ __launch_bounds__(256) void mfma_gemm_t(const unsigned short* __restrict__ A,
                                                   const unsigned short* __restrict__ Wt,
                                                   const float* __restrict__ bias,
                                                   unsigned short* __restrict__ C,
                                                   float* __restrict__ stats,
                                                   const float* __restrict__ bnstats,
                                                   const float* __restrict__ gv,
                                                   const float* __restrict__ bv,
                                                   float invM, int M) {
    __shared__ unsigned short sm[128 * 136];   // staging: [0,16384); epilogue: whole
    __shared__ __align__(16) _Float16 lsc[256];
    __shared__ __align__(16) _Float16 lsh[256];
    __shared__ float sred[256];                // cross-wave stats combine
    unsigned short* As = sm;
    unsigned short* Bs = sm + 128 * 64;
    int tid = threadIdx.x;
    int w = tid >> 6, l = tid & 63;
    int wr = w >> 1, wc = w & 1;

    // bijective XCD-pair block swizzle
    int nRow = (M + 127) >> 7;
    int fullIds = (nRow & ~7) * 2;     // 16 * (nRow/8)
    int id = blockIdx.x;
    int p, cc;
    if (id < fullIds) {
        int gq = id >> 4, r = id & 15;
        cc = r >> 3;
        p = gq * 8 + (r & 7);
    } else {
        int t = id - fullIds;
        p = (nRow & ~7) + (t >> 1);
        cc = t & 1;
    }
    int row0 = p * 128;
    int col0 = cc * 128;

    int g = (l & 7) ^ (l >> 3);      // pre-swizzled source granule
    int srow = w * 8 + (l >> 3);

    if (BN) {
        float sc, sh;
        bn_derive(bnstats, gv, bv, invM, tid, sc, sh);
        lsc[tid] = (_Float16)sc;
        lsh[tid] = (_Float16)sh;
        __syncthreads();
    }

    f32x4 acc[4][4] = {};

    const unsigned short* AB = A + (size_t)row0 * HH;
    const unsigned short* WB = Wt + (size_t)col0 * HH;

    for (int k0 = 0; k0 < 256; k0 += 64) {
#pragma unroll
        for (int r = 0; r < 4; ++r) {
            int row = r * 32 + srow;
            size_t go = (size_t)row * HH + k0 + g * 8;
            int lo = (r * 32 + w * 8) * 64;
            gload16(AB + go, &As[lo]);
            gload16(WB + go, &Bs[lo]);
        }
        __syncthreads();
#pragma unroll
        for (int kh = 0; kh < 2; ++kh) {
            f16x8 af[4], bf[4];
            f16x8 scv, shv;
            if (BN) {
                int kb = k0 + (kh * 4 + (l >> 4)) * 8;
                scv = *(const f16x8*)&lsc[kb];
                shv = *(const f16x8*)&lsh[kb];
            }
#pragma unroll
            for (int m = 0; m < 4; ++m) {
                int rr = wr * 64 + m * 16 + (l & 15);
                int gs = (kh * 4 + (l >> 4)) ^ (rr & 7);
                af[m] = *(const f16x8*)&As[rr * 64 + gs * 8];
                if (BN) {
                    af[m] = af[m] * scv + shv;
                    af[m] = __builtin_elementwise_max(af[m], (f16x8)(_Float16)0);
                }
            }
#pragma unroll
            for (int n = 0; n < 4; ++n) {
                int rr = wc * 64 + n * 16 + (l & 15);
                int gs = (kh * 4 + (l >> 4)) ^ (rr & 7);
                bf[n] = *(const f16x8*)&Bs[rr * 64 + gs * 8];
            }
#pragma unroll
            for (int m = 0; m < 4; ++m)
#pragma unroll
                for (int n = 0; n < 4; ++n)
                    acc[m][n] = __builtin_amdgcn_mfma_f32_16x16x32_f16(af[m], bf[n], acc[m][n], 0, 0, 0);
        }
        __syncthreads();
    }

    // epilogue: bias + C-tile to LDS + per-wave stats accumulation (registers)
    int mvalid = M - row0;
    float sv[4], s2v[4];
#pragma unroll
    for (int n = 0; n < 4; ++n) {
        int colr = wc * 64 + n * 16 + (l & 15);
        float bvv = bias[col0 + colr];
        float s = 0.f, s2 = 0.f;
#pragma unroll
        for (int m = 0; m < 4; ++m) {
            int rb = wr * 64 + m * 16 + (l >> 4) * 4;
#pragma unroll
            for (int r = 0; r < 4; ++r) {
                float v = acc[m][n][r] + bvv;
                sm[(rb + r) * 136 + colr] = f2h(v);
                if (rb + r < mvalid) { s += v; s2 += v * v; }
            }
        }
        s += __shfl_xor(s, 16);   s += __shfl_xor(s, 32);
        s2 += __shfl_xor(s2, 16); s2 += __shfl_xor(s2, 32);
        sv[n] = s;
        s2v[n] = s2;
    }
    // wr=1 deposits partials; wr=0 combines -> one atomic per col per stat
    if (wr == 1 && (l >> 4) == 0) {
#pragma unroll
        for (int n = 0; n < 4; ++n) {
            int colr = wc * 64 + n * 16 + (l & 15);
            sred[colr] = sv[n];
            sred[128 + colr] = s2v[n];
        }
    }
    __syncthreads();   // covers sred AND the sm C-tile
    if (wr == 0 && (l >> 4) == 0) {
#pragma unroll
        for (int n = 0; n < 4; ++n) {
            int colr = wc * 64 + n * 16 + (l & 15);
            atomicAdd(&stats[col0 + colr], sv[n] + sred[colr]);
            atomicAdd(&stats[HH + col0 + colr], s2v[n] + sred[128 + colr]);
        }
    }
#pragma unroll
    for (int i = 0; i < 8; ++i) {
        int ci = i * 256 + tid;          // 0..2047 chunk id
        int row = ci >> 4;
        int cq = (ci & 15) * 8;
        if (row0 + row < M) {
            uint4 v = *(const uint4*)&sm[row * 136 + cq];
            *(uint4*)&C[(size_t)(row0 + row) * HH + col0 + cq] = v;
        }
    }
}

// ---------------- f32 GEMM (classifier), templated on fused BN stats ----------------
template <bool ST>
__global__ __launch_bounds__(256) void gemm_t(const float* __restrict__ A,
                                              const float* __restrict__ W,
                                              const float* __restrict__ bias,
                                              float* __restrict__ C,
                                              float* __restrict__ stats,
                                              int M, int ldw) {
    __shared__ float Asm[64][33];
    __shared__ float Wsm[32][64];
    int tid = threadIdx.x;
    int tx = tid & 15, ty = tid >> 4;
    int row0 = blockIdx.x * 64;
    int col0 = blockIdx.y * 64;
    float acc[4][4] = {};

    for (int k0 = 0; k0 < 256; k0 += 32) {
#pragma unroll
        for (int t = 0; t < 2; ++t) {
            int s = tid + t * 256;
            int m = s >> 3;
            int kq = (s & 7) * 4;
            float4 v = make_float4(0.f, 0.f, 0.f, 0.f);
            if (row0 + m < M) v = *(const float4*)&A[(size_t)(row0 + m) * 256 + k0 + kq];
            Asm[m][kq + 0] = v.x; Asm[m][kq + 1] = v.y; Asm[m][kq + 2] = v.z; Asm[m][kq + 3] = v.w;
        }
#pragma unroll
        for (int t = 0; t < 2; ++t) {
            int s = tid + t * 256;
            int kk = s >> 4;
            int cq = (s & 15) * 4;
            *(float4*)&Wsm[kk][cq] = *(const float4*)&W[(size_t)(k0 + kk) * ldw + col0 + cq];
        }
        __syncthreads();
#pragma unroll
        for (int kk = 0; kk < 32; ++kk) {
            float a0 = Asm[ty * 4 + 0][kk];
            float a1 = Asm[ty * 4 + 1][kk];
            float a2 = Asm[ty * 4 + 2][kk];
            float a3 = Asm[ty * 4 + 3][kk];
            float4 wv = *(const float4*)&Wsm[kk][tx * 4];
            acc[0][0] += a0 * wv.x; acc[0][1] += a0 * wv.y; acc[0][2] += a0 * wv.z; acc[0][3] += a0 * wv.w;
            acc[1][0] += a1 * wv.x; acc[1][1] += a1 * wv.y; acc[1][2] += a1 * wv.z; acc[1][3] += a1 * wv.w;
            acc[2][0] += a2 * wv.x; acc[2][1] += a2 * wv.y; acc[2][2] += a2 * wv.z; acc[2][3] += a2 * wv.w;
            acc[3][0] += a3 * wv.x; acc[3][1] += a3 * wv.y; acc[3][2] += a3 * wv.z; acc[3][3] += a3 * wv.w;
        }
        __syncthreads();
    }

    float4 bvv = *(const float4*)&bias[col0 + tx * 4];
    float s[4] = {}, s2[4] = {};
#pragma unroll
    for (int j = 0; j < 4; ++j) {
        int row = row0 + ty * 4 + j;
        if (row < M) {
            float4 o = make_float4(acc[j][0] + bvv.x, acc[j][1] + bvv.y,
                                   acc[j][2] + bvv.z, acc[j][3] + bvv.w);
            *(float4*)&C[(size_t)row * ldw + col0 + tx * 4] = o;
            if (ST) {
                s[0] += o.x; s2[0] += o.x * o.x;
                s[1] += o.y; s2[1] += o.y * o.y;
                s[2] += o.z; s2[2] += o.z * o.z;
                s[3] += o.w; s2[3] += o.w * o.w;
            }
        }
    }
    if (ST) {
        // intra-wave reduce over ty (lanes tx, tx+16, tx+32, tx+48), then atomic per wave
#pragma unroll
        for (int q = 0; q < 4; ++q) {
            s[q] += __shfl_xor(s[q], 16);  s[q] += __shfl_xor(s[q], 32);
            s2[q] += __shfl_xor(s2[q], 16); s2[q] += __shfl_xor(s2[q], 32);
        }
        if (((tid & 63) >> 4) == 0) {
#pragma unroll
            for (int q = 0; q < 4; ++q) {
                atomicAdd(&stats[col0 + tx * 4 + q], s[q]);
                atomicAdd(&stats[HH + col0 + tx * 4 + q], s2[q]);
            }
        }
    }
}

// classifier f32 in-place apply; BN derive inlined from raw sums
__global__ void bn_apply_relu_kernel(float* __restrict__ X, int n4,
                                     const float* __restrict__ stats,
                                     const float* __restrict__ gv,
                                     const float* __restrict__ bv, float invM) {
    int i = blockIdx.x * blockDim.x + threadIdx.x;
    int stride = gridDim.x * blockDim.x;
    for (; i < n4; i += stride) {
        int c4 = (i & 63) * 4;
        float4 v = ((float4*)X)[i];
        float sc, sh;
        bn_derive(stats, gv, bv, invM, c4 + 0, sc, sh); v.x = fmaxf(v.x * sc + sh, 0.f);
        bn_derive(stats, gv, bv, invM, c4 + 1, sc, sh); v.y = fmaxf(v.y * sc + sh, 0.f);
        bn_derive(stats, gv, bv, invM, c4 + 2, sc, sh); v.z = fmaxf(v.z * sc + sh, 0.f);
        bn_derive(stats, gv, bv, invM, c4 + 3, sc, sh); v.w = fmaxf(v.w * sc + sh, 0.f);
        ((float4*)X)[i] = v;
    }
}

// ---------------- fused mean pool: pooled = mean relu(bn(z2_last)) ----------------
__device__ __forceinline__ int lbound(const int* a, int n, int v) {
    int lo = 0, hi = n;
    while (lo < hi) {
        int mid = (lo + hi) >> 1;
        if (a[mid] < v) lo = mid + 1; else hi = mid;
    }
    return lo;
}

__global__ void pool_fused_kernel(const unsigned short* __restrict__ Hm,
                                  const int* __restrict__ batch,
                                  const float* __restrict__ stats,
                                  const float* __restrict__ gv,
                                  const float* __restrict__ bv, float invM,
                                  int N, float* __restrict__ pooled) {
    int g = blockIdx.x;
    int c = threadIdx.x;
    int s = lbound(batch, N, g);
    int e = lbound(batch, N, g + 1);
    float sc, sh;
    bn_derive(stats, gv, bv, invM, c, sc, sh);
    float acc = 0.f;
    for (int r = s; r < e; ++r)
        acc += fmaxf(h2f(Hm[(size_t)r * HH + c]) * sc + sh, 0.f);
    pooled[(size_t)g * HH + c] = acc / (float)max(e - s, 1);
}

// ---------------- launch ----------------
extern "C" void kernel_launch(void* const* d_in, const int* in_sizes, int n_in,
                              void* d_out, int out_size, void* d_ws, size_t ws_size,
                              hipStream_t stream) {
    const float* x_atom = (const float*)d_in[0];
    const float* x_pe   = (const float*)d_in[1];
    const int* ei       = (const int*)d_in[2];
    const int* batch    = (const int*)d_in[3];
    const float* ae_w = (const float*)d_in[4];
    const float* ae_b = (const float*)d_in[5];
    const float* pe_w = (const float*)d_in[6];
    const float* pe_b = (const float*)d_in[7];
    const float* w1  = (const float*)d_in[8];
    const float* b1  = (const float*)d_in[9];
    const float* g1  = (const float*)d_in[10];
    const float* be1 = (const float*)d_in[11];
    const float* w2  = (const float*)d_in[12];
    const float* b2  = (const float*)d_in[13];
    const float* bng = (const float*)d_in[14];
    const float* bnb = (const float*)d_in[15];
    const float* cl1_w = (const float*)d_in[16];
    const float* cl1_b = (const float*)d_in[17];
    const float* clg = (const float*)d_in[18];
    const float* clb = (const float*)d_in[19];
    const float* cl2_w = (const float*)d_in[20];
    const float* cl2_b = (const float*)d_in[21];

    const int N = in_sizes[3];
    const int E = in_sizes[2] / 2;
    const int T = in_sizes[21];
    const int B = out_size / T;
    const int Lnum = in_sizes[9] / HH;
    const int nc = cdiv(N, CHUNK);
    const int Npad = cdiv(N, 128) * 128;
    const size_t P = (size_t)Npad * HH;

    unsigned short* X = (unsigned short*)d_ws;
    unsigned short* Y = X + P;
    unsigned short* wt1 = Y + P;                        // L*HH*HH f16
    unsigned short* wt2 = wt1 + (size_t)Lnum * HH * HH;
    float* stats = (float*)(wt2 + (size_t)Lnum * HH * HH);   // NSLOT x 4*HH
    float* pooled = stats + (size_t)NSLOT * 4 * HH;
    float* zc = pooled + (size_t)B * HH;
    int* deg = (int*)(zc + (size_t)B * HH);
    int* offs = deg + N;
    int* cursor = offs + N + 1;
    int* chunkSum = cursor + N;
    int* chunkOff = chunkSum + 256;
    int* srcl = chunkOff + 256;

    const int BH4 = B * (HH / 4);
    const float invN = 1.f / (float)N;

    // ---- setup (deg + stats zero, one launch) ----
    setup_kernel<<<cdiv(max(N, NSLOT * 512), 256), 256, 0, stream>>>(deg, N, stats);

    // ---- CSR build ----
    hist_kernel<<<cdiv(E, 256), 256, 0, stream>>>(ei, deg, E);
    ps1_kernel<<<nc, CHUNK, 0, stream>>>(deg, chunkSum, N);
    ps2_kernel<<<1, CHUNK, 0, stream>>>(chunkSum, chunkOff, nc, offs, N, E);
    ps3_kernel<<<nc, CHUNK, 0, stream>>>(deg, chunkOff, offs, cursor, N);
    fill_kernel<<<cdiv(E, 256), 256, 0, stream>>>(ei, cursor, srcl, E);

    // ---- weight transpose (both sets, one launch) ----
    transpose_w_kernel<<<2 * Lnum * 64, 256, 0, stream>>>(w1, w2, wt1, wt2, Lnum * 64);

    // ---- embed (wave per node) ----
    embed_kernel<<<cdiv(N, 4), 256, 0, stream>>>(x_atom, x_pe, ae_w, ae_b, pe_w, pe_b, X, N);

    const int nRow = cdiv(N, 128);
    const int mf_blocks = 2 * nRow;   // 1D grid, XCD-pair swizzle inside

    unsigned short *in = X, *ot = Y;

    for (int i = 0; i < Lnum; ++i) {
        float* slot1 = stats + (size_t)(2 * i) * 4 * HH;
        float* slot2 = stats + (size_t)(2 * i + 1) * 4 * HH;
        const float* aggStats = (i == 0) ? nullptr : stats + (size_t)(2 * i - 1) * 4 * HH;
        const float* aggG = (i == 0) ? nullptr : bng + (size_t)(i - 1) * HH;
        const float* aggB = (i == 0) ? nullptr : bnb + (size_t)(i - 1) * HH;

        // z = t(in) + gather-sum t(in[src]) : in -> ot
        aggregate_fused_kernel<<<cdiv(N, 4), 256, 0, stream>>>(in, offs, srcl,
                                                               aggStats, aggG, aggB, invN, ot, N);

        // z1 = z @ w1 + b1 : ot -> in (raw z1; inner BN applied in GEMM2 fragments)
        mfma_gemm_t<false><<<mf_blocks, 256, 0, stream>>>(ot, wt1 + (size_t)i * HH * HH,
                                                          b1 + (size_t)i * HH, in, slot1,
                                                          nullptr, nullptr, nullptr, 0.f, N);

        // z2 = relu(bn(z1)) @ w2 + b2 : in -> ot (BN on A fragments, async staging kept)
        mfma_gemm_t<true><<<mf_blocks, 256, 0, stream>>>(in, wt2 + (size_t)i * HH * HH,
                                                         b2 + (size_t)i * HH, ot, slot2,
                                                         slot1, g1 + (size_t)i * HH,
                                                         be1 + (size_t)i * HH, invN, N);

        unsigned short* t = in; in = ot; ot = t;
    }

    // ---- fused mean pool (applies last outer BN+relu) ----
    pool_fused_kernel<<<B, HH, 0, stream>>>(in, batch,
                                            stats + (size_t)(2 * Lnum - 1) * 4 * HH,
                                            bng + (size_t)(Lnum - 1) * HH,
                                            bnb + (size_t)(Lnum - 1) * HH, invN, N, pooled);

    // ---- classifier (f32 path, slot 10): gemm1(+stats) -> apply(derive) -> gemm2 ----
    float* slotC = stats + (size_t)10 * 4 * HH;
    dim3 cls_grid1(cdiv(B, 64), HH / 64);
    gemm_t<true><<<cls_grid1, 256, 0, stream>>>(pooled, cl1_w, cl1_b, zc, slotC, B, HH);
    bn_apply_relu_kernel<<<min(2048, cdiv(BH4, 256)), 256, 0, stream>>>(zc, BH4, slotC,
                                                                        clg, clb, 1.f / B);

    dim3 cls_grid2(cdiv(B, 64), T / 64);
    gemm_t<false><<<cls_grid2, 256, 0, stream>>>(zc, cl2_w, cl2_b, (float*)d_out, nullptr, B, T);
}